// Round 1
// baseline (1550.937 us; speedup 1.0000x reference)
//
#include <hip/hip_runtime.h>
#include <math.h>

#define N_ROWS 16384
#define DIM 1024
#define KC 32
#define LF 16
#define LOG2PI_F 1.8378770664093453f

// ---- workspace layout (float offsets) ----
#define O_WE     0              // [1024][576] packed E-step operand: cols 0..511 B=iD*A (k*16+l), 512..543 iD*MU, 544..575 iD
#define WE_STRIDE 576
#define O_WQ     589824         // [1024][512] packed A (k*16+l)
#define O_Y      1114112        // [16384][592] E-step GEMM output (cols 0..575 used); ALIASED as RQ [16384][512] later
#define Y_STRIDE 592
#define O_RQ     O_Y
#define O_R      10813440       // [16384][32] responsibilities
#define O_XSQ    11337728       // [16384]
#define O_LMAT   11354112       // [32][256] L = I + A^T(iD A)
#define O_M0     11362304       // [32][256] A^T A + s2 I
#define O_IL     11370496       // [32][256] inv(L)
#define O_INVM   11378688       // [32][256] inv(M0)
#define O_GM     11386880       // [32][256] s2 I + invM @ ATSiAi
#define O_IG     11395072       // [32][256] inv(GM)
#define O_CB     11403264       // [32][16]  MU . B
#define O_CA     11403776       // [32][16]  mu_new . A
#define O_CONST  11404288       // [32] sum iD*MU^2
#define O_SLD    11404320       // [32] sum log_D
#define O_LDET   11404352       // [32] logdet(L)
#define O_PIK    11404384       // [32] softmax(PI_logits)
#define O_CK     11404416       // [32] folded per-k constant
#define O_MUSQ   11404448       // [32] ||mu_new||^2
// --- zeroed accumulator block (single memset) ---
#define O_SIAI   11404480       // [1024][512] SiAi_raw = X^T @ RQ
#define O_MUACC  11928768       // [32][1024] r^T x
#define O_SUMRQ  11961536       // [512]
#define O_RSUM   11962048       // [32]
#define O_RXSQ   11962080       // [32]
#define O_T1     11962112       // [32]
#define ZERO_START O_SIAI
#define ZERO_COUNT 557664

// d_out layout
#define OU_MU 0
#define OU_A  32768
#define OU_LD 557056
#define OU_PI 589824

__device__ __forceinline__ float blockReduce256(float v, float* red) {
    int tid = threadIdx.x;
    red[tid] = v; __syncthreads();
    for (int s = 128; s > 0; s >>= 1) {
        if (tid < s) red[tid] += red[tid + s];
        __syncthreads();
    }
    float r = red[0]; __syncthreads();
    return r;
}

// ---------------- prep: pack operands, per-k small matrices ----------------
__global__ __launch_bounds__(256) void k_prep(
    const float* __restrict__ MU, const float* __restrict__ A,
    const float* __restrict__ logD, const float* __restrict__ PIl,
    float* __restrict__ ws)
{
    int k = blockIdx.x, tid = threadIdx.x;
    __shared__ float red[256];
    float* We = ws + O_WE;
    float* Wq = ws + O_WQ;

    float cb[LF];
    #pragma unroll
    for (int l = 0; l < LF; l++) cb[l] = 0.f;
    float cst = 0.f, sl = 0.f;

    for (int dd = tid; dd < DIM; dd += 256) {
        float ld  = logD[k*DIM + dd];
        float idv = expf(-ld);
        float mu  = MU[k*DIM + dd];
        cst += idv*mu*mu;
        sl  += ld;
        const float* arow = A + (size_t)(k*DIM + dd)*LF;
        float* werow = We + (size_t)dd*WE_STRIDE;
        float* wqrow = Wq + (size_t)dd*512;
        #pragma unroll
        for (int l = 0; l < LF; l++) {
            float a = arow[l];
            float b = idv*a;
            werow[k*LF + l] = b;
            wqrow[k*LF + l] = a;
            cb[l] += mu*b;
        }
        werow[512 + k] = idv*mu;
        werow[544 + k] = idv;
    }

    for (int l = 0; l < LF; l++) {
        float t = blockReduce256(cb[l], red);
        if (tid == 0) ws[O_CB + k*LF + l] = t;
    }
    {
        float t = blockReduce256(cst, red);
        if (tid == 0) ws[O_CONST + k] = t;
        t = blockReduce256(sl, red);
        if (tid == 0) ws[O_SLD + k] = t;
    }
    if (tid == 0) {
        float mx = -1e30f;
        for (int j = 0; j < KC; j++) mx = fmaxf(mx, PIl[j]);
        float s = 0.f;
        for (int j = 0; j < KC; j++) s += expf(PIl[j] - mx);
        ws[O_PIK + k] = expf(PIl[k] - mx) / s;
    }
    __syncthreads();

    // L = I + A^T (iD A), M0 = s2 I + A^T A ; entry (i,j) per thread
    int i = tid >> 4, j = tid & 15;
    float sL = 0.f, sM = 0.f;
    for (int dd = 0; dd < DIM; dd++) {
        const float* arow = A + (size_t)(k*DIM + dd)*LF;
        float ai = arow[i], aj = arow[j];
        float idv = We[(size_t)dd*WE_STRIDE + 544 + k];   // reuse packed iD
        sL += ai*aj*idv;
        sM += ai*aj;
    }
    float s2 = expf(logD[k*DIM]);
    ws[O_LMAT + k*256 + tid] = sL + (i == j ? 1.f : 0.f);
    ws[O_M0   + k*256 + tid] = sM + (i == j ? s2  : 0.f);
}

// ---------------- batched 16x16 inversion (Gauss-Jordan, partial pivot) ----------------
__global__ __launch_bounds__(256) void k_inv16(const float* __restrict__ src,
    float* __restrict__ dst, float* __restrict__ ldet)
{
    __shared__ float M[16][33];
    __shared__ float fac[16];
    __shared__ int spv;
    __shared__ float sld;
    int m = blockIdx.x, tid = threadIdx.x;

    for (int idx = tid; idx < 16*33; idx += 256) {
        int i = idx/33, c = idx%33;
        M[i][c] = (c < 16) ? src[m*256 + i*16 + c]
                           : (c < 32 ? ((i == c-16) ? 1.f : 0.f) : 0.f);
    }
    if (tid == 0) sld = 0.f;
    __syncthreads();

    for (int j = 0; j < 16; j++) {
        if (tid == 0) {
            int p = j; float best = fabsf(M[j][j]);
            for (int i2 = j+1; i2 < 16; i2++) {
                float a = fabsf(M[i2][j]);
                if (a > best) { best = a; p = i2; }
            }
            spv = p;
            sld += logf(fabsf(M[p][j]));
        }
        __syncthreads();
        int p = spv;
        if (p != j && tid < 33) { float t = M[j][tid]; M[j][tid] = M[p][tid]; M[p][tid] = t; }
        __syncthreads();
        float pv = M[j][j];
        __syncthreads();
        if (tid < 33) M[j][tid] = M[j][tid] / pv;
        __syncthreads();
        if (tid < 16) fac[tid] = M[tid][j];
        __syncthreads();
        for (int idx = tid; idx < 16*33; idx += 256) {
            int i2 = idx/33, c = idx%33;
            if (i2 != j) M[i2][c] -= fac[i2]*M[j][c];
        }
        __syncthreads();
    }
    {
        int i = tid >> 4, c = tid & 15;
        dst[m*256 + tid] = M[i][16 + c];
    }
    if (ldet != nullptr && tid == 0) ldet[m] = sld;
}

// ---------------- fold per-k constants ----------------
__global__ void k_prep2(float* __restrict__ ws)
{
    int k = threadIdx.x;
    if (k < KC) {
        ws[O_CK + k] = ws[O_PIK + k]
            - 0.5f*((float)DIM*LOG2PI_F + ws[O_LDET + k] + ws[O_SLD + k] + ws[O_CONST + k]);
    }
}

// ---------------- G1: Y = X @ We (+ x^2 for sq columns), xsq ----------------
__global__ __launch_bounds__(256) void k_g1(const float* __restrict__ x,
    const float* __restrict__ We, float* __restrict__ Y, float* __restrict__ xsq)
{
    __shared__ float xs[64][68];    // [row][dd]
    __shared__ float wl[64][132];   // [dd][col]
    int tid = threadIdx.x;
    int r0b = blockIdx.x*64;
    int tr = tid >> 4, tc = tid & 15;
    float xsq_p[4] = {0.f,0.f,0.f,0.f};

    for (int cc0 = 0; cc0 < 576; cc0 += 128) {
        float acc[4][8];
        #pragma unroll
        for (int i = 0; i < 4; i++)
            #pragma unroll
            for (int j = 0; j < 8; j++) acc[i][j] = 0.f;

        bool sqA = (cc0 + tc*4)      >= 544;
        bool sqB = (cc0 + 64 + tc*4) >= 544;
        bool doXsq = (cc0 == 0 && tc == 0);

        for (int dd0 = 0; dd0 < DIM; dd0 += 64) {
            __syncthreads();
            #pragma unroll
            for (int it = 0; it < 4; it++) {
                int idx = tid + it*256;
                int row = idx >> 4, col4 = (idx & 15)*4;
                *(float4*)&xs[row][col4] =
                    *(const float4*)&x[(size_t)(r0b + row)*DIM + dd0 + col4];
            }
            #pragma unroll
            for (int it = 0; it < 8; it++) {
                int idx = tid + it*256;
                int dd = idx >> 5, col4 = (idx & 31)*4;
                int c = cc0 + col4;
                float4 v;
                if (c < 576) v = *(const float4*)&We[(size_t)(dd0 + dd)*WE_STRIDE + c];
                else v = make_float4(0.f,0.f,0.f,0.f);
                *(float4*)&wl[dd][col4] = v;
            }
            __syncthreads();

            for (int dd = 0; dd < 64; dd++) {
                float xv[4];
                #pragma unroll
                for (int i = 0; i < 4; i++) xv[i] = xs[tr*4 + i][dd];
                if (doXsq) {
                    #pragma unroll
                    for (int i = 0; i < 4; i++) xsq_p[i] += xv[i]*xv[i];
                }
                float4 wa = *(float4*)&wl[dd][tc*4];
                float4 wb = *(float4*)&wl[dd][64 + tc*4];
                float xa[4], xb[4];
                #pragma unroll
                for (int i = 0; i < 4; i++) {
                    xa[i] = sqA ? xv[i]*xv[i] : xv[i];
                    xb[i] = sqB ? xv[i]*xv[i] : xv[i];
                }
                #pragma unroll
                for (int i = 0; i < 4; i++) {
                    acc[i][0] += xa[i]*wa.x; acc[i][1] += xa[i]*wa.y;
                    acc[i][2] += xa[i]*wa.z; acc[i][3] += xa[i]*wa.w;
                    acc[i][4] += xb[i]*wb.x; acc[i][5] += xb[i]*wb.y;
                    acc[i][6] += xb[i]*wb.z; acc[i][7] += xb[i]*wb.w;
                }
            }
        }
        #pragma unroll
        for (int i = 0; i < 4; i++) {
            int row = r0b + tr*4 + i;
            int ca = cc0 + tc*4;
            *(float4*)&Y[(size_t)row*Y_STRIDE + ca] =
                make_float4(acc[i][0], acc[i][1], acc[i][2], acc[i][3]);
            int cbn = cc0 + 64 + tc*4;
            if (cbn < 576)
                *(float4*)&Y[(size_t)row*Y_STRIDE + cbn] =
                    make_float4(acc[i][4], acc[i][5], acc[i][6], acc[i][7]);
        }
        if (doXsq) {
            #pragma unroll
            for (int i = 0; i < 4; i++) xsq[r0b + tr*4 + i] = xsq_p[i];
        }
    }
}

// ---------------- E-step epilogue: responsibilities ----------------
__global__ __launch_bounds__(256) void k_epiE(const float* __restrict__ Y,
    const float* __restrict__ iL, const float* __restrict__ cB,
    const float* __restrict__ Ck, const float* __restrict__ xsq,
    float* __restrict__ rr, float* __restrict__ rsum, float* __restrict__ rxsq)
{
    __shared__ float iLs[32*257];
    __shared__ float yr[8*Y_STRIDE];
    __shared__ float cBs[512];
    __shared__ float rs_s[32], rx_s[32];
    int tid = threadIdx.x;
    int n0 = blockIdx.x*8;

    for (int idx = tid; idx < 8192; idx += 256)
        iLs[(idx >> 8)*257 + (idx & 255)] = iL[idx];
    for (int idx = tid; idx < 512; idx += 256) cBs[idx] = cB[idx];
    for (int idx = tid; idx < 8*Y_STRIDE; idx += 256)
        yr[idx] = Y[(size_t)n0*Y_STRIDE + idx];
    if (tid < 32) { rs_s[tid] = 0.f; rx_s[tid] = 0.f; }
    __syncthreads();

    int row = tid >> 5, k = tid & 31;
    const float* yrow = yr + row*Y_STRIDE;
    float y[16];
    #pragma unroll
    for (int j = 0; j < 16; j++) y[j] = yrow[k*16 + j] - cBs[k*16 + j];
    float t2 = 0.f;
    for (int i2 = 0; i2 < 16; i2++) {
        float ti = 0.f;
        const float* ilr = iLs + k*257 + i2*16;
        #pragma unroll
        for (int j = 0; j < 16; j++) ti += ilr[j]*y[j];
        t2 += y[i2]*ti;
    }
    float cross = yrow[512 + k];
    float sq    = yrow[544 + k];
    float cll = Ck[k] + cross - 0.5f*sq + 0.5f*t2;

    float mx = cll;
    #pragma unroll
    for (int m = 16; m >= 1; m >>= 1) mx = fmaxf(mx, __shfl_xor(mx, m, 32));
    float e = __expf(cll - mx);
    float ssum = e;
    #pragma unroll
    for (int m = 16; m >= 1; m >>= 1) ssum += __shfl_xor(ssum, m, 32);
    float rv = e / ssum;

    rr[(size_t)(n0 + row)*KC + k] = rv;
    atomicAdd(&rs_s[k], rv);
    atomicAdd(&rx_s[k], rv*xsq[n0 + row]);
    __syncthreads();
    if (tid < 32) {
        atomicAdd(&rsum[tid], rs_s[tid]);
        atomicAdd(&rxsq[tid], rx_s[tid]);
    }
}

// ---------------- mu accumulation: muacc = r^T x ----------------
__global__ __launch_bounds__(256) void k_mu(const float* __restrict__ x,
    const float* __restrict__ rr, float* __restrict__ muacc)
{
    __shared__ float rl[8][32];
    int tid = threadIdx.x;
    int d0 = blockIdx.x*128;
    int n0 = blockIdx.y*512;
    int dd = d0 + (tid & 127);
    int kg = (tid >> 7)*16;
    float acc[16];
    #pragma unroll
    for (int j = 0; j < 16; j++) acc[j] = 0.f;

    for (int nb = 0; nb < 512; nb += 8) {
        __syncthreads();
        rl[tid >> 5][tid & 31] = rr[(size_t)(n0 + nb + (tid >> 5))*KC + (tid & 31)];
        __syncthreads();
        for (int r2 = 0; r2 < 8; r2++) {
            float xv = x[(size_t)(n0 + nb + r2)*DIM + dd];
            #pragma unroll
            for (int j = 0; j < 16; j++) acc[j] += rl[r2][kg + j]*xv;
        }
    }
    #pragma unroll
    for (int j = 0; j < 16; j++)
        atomicAdd(&muacc[(size_t)(kg + j)*DIM + dd], acc[j]);
}

// ---------------- finalize mu, cA, musq ----------------
__global__ __launch_bounds__(256) void k_mufin(const float* __restrict__ muacc,
    const float* __restrict__ rsum, const float* __restrict__ A,
    float* __restrict__ out_mu, float* __restrict__ cA, float* __restrict__ musq)
{
    __shared__ float red[256];
    int k = blockIdx.x, tid = threadIdx.x;
    float rs = rsum[k];
    float ca[16];
    #pragma unroll
    for (int l = 0; l < 16; l++) ca[l] = 0.f;
    float msq = 0.f;
    for (int dd = tid; dd < DIM; dd += 256) {
        float m = muacc[(size_t)k*DIM + dd] / rs;
        out_mu[(size_t)k*DIM + dd] = m;
        msq += m*m;
        const float* arow = A + (size_t)(k*DIM + dd)*LF;
        #pragma unroll
        for (int l = 0; l < 16; l++) ca[l] += m*arow[l];
    }
    for (int l = 0; l < 16; l++) {
        float t = blockReduce256(ca[l], red);
        if (tid == 0) cA[k*16 + l] = t;
    }
    float t = blockReduce256(msq, red);
    if (tid == 0) musq[k] = t;
}

// ---------------- G2: RQ = r * (X@A - cA), sumRQ ----------------
__global__ __launch_bounds__(256) void k_g2(const float* __restrict__ x,
    const float* __restrict__ Wq, const float* __restrict__ rr,
    const float* __restrict__ cA, float* __restrict__ RQ, float* __restrict__ sumRQ)
{
    __shared__ float xs[64][68];
    __shared__ float wl[64][132];
    __shared__ float sred[16][128];
    int tid = threadIdx.x;
    int r0b = blockIdx.x*64;
    int tr = tid >> 4, tc = tid & 15;

    for (int cc0 = 0; cc0 < 512; cc0 += 128) {
        float acc[4][8];
        #pragma unroll
        for (int i = 0; i < 4; i++)
            #pragma unroll
            for (int j = 0; j < 8; j++) acc[i][j] = 0.f;

        for (int dd0 = 0; dd0 < DIM; dd0 += 64) {
            __syncthreads();
            #pragma unroll
            for (int it = 0; it < 4; it++) {
                int idx = tid + it*256;
                int row = idx >> 4, col4 = (idx & 15)*4;
                *(float4*)&xs[row][col4] =
                    *(const float4*)&x[(size_t)(r0b + row)*DIM + dd0 + col4];
            }
            #pragma unroll
            for (int it = 0; it < 8; it++) {
                int idx = tid + it*256;
                int dd = idx >> 5, col4 = (idx & 31)*4;
                *(float4*)&wl[dd][col4] =
                    *(const float4*)&Wq[(size_t)(dd0 + dd)*512 + cc0 + col4];
            }
            __syncthreads();
            for (int dd = 0; dd < 64; dd++) {
                float xv[4];
                #pragma unroll
                for (int i = 0; i < 4; i++) xv[i] = xs[tr*4 + i][dd];
                float4 wa = *(float4*)&wl[dd][tc*4];
                float4 wb = *(float4*)&wl[dd][64 + tc*4];
                #pragma unroll
                for (int i = 0; i < 4; i++) {
                    acc[i][0] += xv[i]*wa.x; acc[i][1] += xv[i]*wa.y;
                    acc[i][2] += xv[i]*wa.z; acc[i][3] += xv[i]*wa.w;
                    acc[i][4] += xv[i]*wb.x; acc[i][5] += xv[i]*wb.y;
                    acc[i][6] += xv[i]*wb.z; acc[i][7] += xv[i]*wb.w;
                }
            }
        }
        int ca = cc0 + tc*4, cbn = cc0 + 64 + tc*4;
        int ka = ca >> 4, kb = cbn >> 4;
        float4 cAa = *(const float4*)&cA[ka*16 + (ca & 15)];
        float4 cAb = *(const float4*)&cA[kb*16 + (cbn & 15)];
        float spa[4] = {0.f,0.f,0.f,0.f}, spb[4] = {0.f,0.f,0.f,0.f};
        #pragma unroll
        for (int i = 0; i < 4; i++) {
            int row = r0b + tr*4 + i;
            float rva = rr[(size_t)row*KC + ka];
            float rvb = rr[(size_t)row*KC + kb];
            float q0 = (acc[i][0]-cAa.x)*rva, q1 = (acc[i][1]-cAa.y)*rva;
            float q2 = (acc[i][2]-cAa.z)*rva, q3 = (acc[i][3]-cAa.w)*rva;
            float q4 = (acc[i][4]-cAb.x)*rvb, q5 = (acc[i][5]-cAb.y)*rvb;
            float q6 = (acc[i][6]-cAb.z)*rvb, q7 = (acc[i][7]-cAb.w)*rvb;
            *(float4*)&RQ[(size_t)row*512 + ca]  = make_float4(q0,q1,q2,q3);
            *(float4*)&RQ[(size_t)row*512 + cbn] = make_float4(q4,q5,q6,q7);
            spa[0]+=q0; spa[1]+=q1; spa[2]+=q2; spa[3]+=q3;
            spb[0]+=q4; spb[1]+=q5; spb[2]+=q6; spb[3]+=q7;
        }
        __syncthreads();
        #pragma unroll
        for (int j = 0; j < 4; j++) {
            sred[tr][tc*4 + j]      = spa[j];
            sred[tr][64 + tc*4 + j] = spb[j];
        }
        __syncthreads();
        if (tid < 128) {
            float s = 0.f;
            #pragma unroll
            for (int g = 0; g < 16; g++) s += sred[g][tid];
            atomicAdd(&sumRQ[cc0 + tid], s);
        }
        __syncthreads();
    }
}

// ---------------- G3: SiAi_raw += X^T @ RQ ----------------
__global__ __launch_bounds__(256) void k_g3(const float* __restrict__ x,
    const float* __restrict__ RQ, float* __restrict__ SiAi)
{
    __shared__ float xsn[64][68];    // [nn][dd]
    __shared__ float rqn[64][132];   // [nn][c]
    int tid = threadIdx.x, tr = tid >> 4, tc = tid & 15;
    int dd0 = blockIdx.x*64;
    int c0  = blockIdx.y*128;
    int nbase = blockIdx.z*2048;
    float acc[4][8];
    #pragma unroll
    for (int i = 0; i < 4; i++)
        #pragma unroll
        for (int j = 0; j < 8; j++) acc[i][j] = 0.f;

    for (int n0 = nbase; n0 < nbase + 2048; n0 += 64) {
        __syncthreads();
        #pragma unroll
        for (int it = 0; it < 4; it++) {
            int idx = tid + it*256;
            int nn = idx >> 4, col4 = (idx & 15)*4;
            *(float4*)&xsn[nn][col4] =
                *(const float4*)&x[(size_t)(n0 + nn)*DIM + dd0 + col4];
        }
        #pragma unroll
        for (int it = 0; it < 8; it++) {
            int idx = tid + it*256;
            int nn = idx >> 5, col4 = (idx & 31)*4;
            *(float4*)&rqn[nn][col4] =
                *(const float4*)&RQ[(size_t)(n0 + nn)*512 + c0 + col4];
        }
        __syncthreads();
        for (int nn = 0; nn < 64; nn++) {
            float4 a  = *(float4*)&xsn[nn][tr*4];
            float4 b0 = *(float4*)&rqn[nn][tc*4];
            float4 b1 = *(float4*)&rqn[nn][64 + tc*4];
            float av[4] = {a.x, a.y, a.z, a.w};
            #pragma unroll
            for (int i = 0; i < 4; i++) {
                acc[i][0] += av[i]*b0.x; acc[i][1] += av[i]*b0.y;
                acc[i][2] += av[i]*b0.z; acc[i][3] += av[i]*b0.w;
                acc[i][4] += av[i]*b1.x; acc[i][5] += av[i]*b1.y;
                acc[i][6] += av[i]*b1.z; acc[i][7] += av[i]*b1.w;
            }
        }
    }
    #pragma unroll
    for (int i = 0; i < 4; i++) {
        size_t dd = dd0 + tr*4 + i;
        #pragma unroll
        for (int j = 0; j < 4; j++) {
            atomicAdd(&SiAi[dd*512 + c0 + tc*4 + j],      acc[i][j]);
            atomicAdd(&SiAi[dd*512 + c0 + 64 + tc*4 + j], acc[i][4 + j]);
        }
    }
}

// ---------------- ATSiAi and Gm ----------------
__global__ __launch_bounds__(256) void k_ats(const float* __restrict__ A,
    const float* __restrict__ logD, const float* __restrict__ SiAi,
    const float* __restrict__ cA, const float* __restrict__ sumRQ,
    const float* __restrict__ rsum, const float* __restrict__ invM,
    float* __restrict__ Gm)
{
    __shared__ float atsl[256];
    int k = blockIdx.x, tid = threadIdx.x, i = tid >> 4, j = tid & 15;
    float s = 0.f;
    for (int dd = 0; dd < DIM; dd++) {
        s += A[((size_t)k*DIM + dd)*LF + i] * SiAi[(size_t)dd*512 + k*16 + j];
    }
    float av = (s - cA[k*16 + i]*sumRQ[k*16 + j]) / rsum[k];
    atsl[tid] = av;
    __syncthreads();
    float s2 = expf(logD[k*DIM]);
    float g = (i == j) ? s2 : 0.f;
    #pragma unroll
    for (int m = 0; m < 16; m++) g += invM[k*256 + i*16 + m]*atsl[m*16 + j];
    Gm[k*256 + tid] = g;
}

// ---------------- A_new rows + t1 ----------------
__global__ __launch_bounds__(256) void k_anew(const float* __restrict__ SiAi,
    const float* __restrict__ mu_out, const float* __restrict__ sumRQ,
    const float* __restrict__ rsum, const float* __restrict__ iG,
    const float* __restrict__ invM, float* __restrict__ outA, float* __restrict__ t1)
{
    __shared__ float iGs[256], iMs[256];
    __shared__ float red[256];
    int k = blockIdx.x, tid = threadIdx.x;
    int dd = blockIdx.y*256 + tid;
    iGs[tid] = iG[k*256 + tid];
    iMs[tid] = invM[k*256 + tid];
    __syncthreads();
    float rs = rsum[k];
    float mv = mu_out[(size_t)k*DIM + dd];
    float sr[16];
    #pragma unroll
    for (int j = 0; j < 16; j++)
        sr[j] = (SiAi[(size_t)dd*512 + k*16 + j] - mv*sumRQ[k*16 + j]) / rs;
    float t1p = 0.f;
    float an[16];
    #pragma unroll
    for (int j = 0; j < 16; j++) {
        float a = 0.f, b = 0.f;
        #pragma unroll
        for (int m = 0; m < 16; m++) {
            a += sr[m]*iGs[m*16 + j];
            b += sr[m]*iMs[m*16 + j];
        }
        an[j] = a;
        t1p += a*b;
    }
    #pragma unroll
    for (int j = 0; j < 16; j += 4)
        *(float4*)&outA[((size_t)k*DIM + dd)*LF + j] =
            make_float4(an[j], an[j+1], an[j+2], an[j+3]);
    red[tid] = t1p; __syncthreads();
    for (int s = 128; s > 0; s >>= 1) {
        if (tid < s) red[tid] += red[tid + s];
        __syncthreads();
    }
    if (tid == 0) atomicAdd(&t1[k], red[0]);
}

// ---------------- final: log_D_new, PI_logits_new ----------------
__global__ __launch_bounds__(256) void k_final(const float* __restrict__ rsum,
    const float* __restrict__ rxsq, const float* __restrict__ musq,
    const float* __restrict__ t1, float* __restrict__ out)
{
    int k = blockIdx.x, tid = threadIdx.x;
    float rs = rsum[k];
    float ts = (rxsq[k] - rs*musq[k]) / rs;
    float sig = (ts - t1[k]) / (float)DIM;
    float ld = logf(sig);
    for (int dd = tid; dd < DIM; dd += 256)
        out[OU_LD + (size_t)k*DIM + dd] = ld;
    if (tid == 0) {
        float s = 0.f;
        for (int j = 0; j < KC; j++) s += rsum[j];
        out[OU_PI + k] = logf(rs / s);
    }
}

extern "C" void kernel_launch(void* const* d_in, const int* in_sizes, int n_in,
                              void* d_out, int out_size, void* d_ws, size_t ws_size,
                              hipStream_t stream) {
    const float* x    = (const float*)d_in[0];
    const float* MU   = (const float*)d_in[1];
    const float* A    = (const float*)d_in[2];
    const float* logD = (const float*)d_in[3];
    const float* PIl  = (const float*)d_in[4];
    float* out = (float*)d_out;
    float* ws  = (float*)d_ws;

    // zero the accumulator block
    hipMemsetAsync(ws + ZERO_START, 0, (size_t)ZERO_COUNT*sizeof(float), stream);

    k_prep<<<KC, 256, 0, stream>>>(MU, A, logD, PIl, ws);
    k_inv16<<<KC, 256, 0, stream>>>(ws + O_LMAT, ws + O_IL, ws + O_LDET);
    k_inv16<<<KC, 256, 0, stream>>>(ws + O_M0, ws + O_INVM, nullptr);
    k_prep2<<<1, 32, 0, stream>>>(ws);

    k_g1<<<N_ROWS/64, 256, 0, stream>>>(x, ws + O_WE, ws + O_Y, ws + O_XSQ);
    k_epiE<<<N_ROWS/8, 256, 0, stream>>>(ws + O_Y, ws + O_IL, ws + O_CB, ws + O_CK,
                                         ws + O_XSQ, ws + O_R, ws + O_RSUM, ws + O_RXSQ);

    k_mu<<<dim3(8, 32), 256, 0, stream>>>(x, ws + O_R, ws + O_MUACC);
    k_mufin<<<KC, 256, 0, stream>>>(ws + O_MUACC, ws + O_RSUM, A,
                                    out + OU_MU, ws + O_CA, ws + O_MUSQ);

    k_g2<<<N_ROWS/64, 256, 0, stream>>>(x, ws + O_WQ, ws + O_R, ws + O_CA,
                                        ws + O_RQ, ws + O_SUMRQ);
    k_g3<<<dim3(16, 4, 8), 256, 0, stream>>>(x, ws + O_RQ, ws + O_SIAI);

    k_ats<<<KC, 256, 0, stream>>>(A, logD, ws + O_SIAI, ws + O_CA, ws + O_SUMRQ,
                                  ws + O_RSUM, ws + O_INVM, ws + O_GM);
    k_inv16<<<KC, 256, 0, stream>>>(ws + O_GM, ws + O_IG, nullptr);
    k_anew<<<dim3(KC, 4), 256, 0, stream>>>(ws + O_SIAI, out + OU_MU, ws + O_SUMRQ,
                                            ws + O_RSUM, ws + O_IG, ws + O_INVM,
                                            out + OU_A, ws + O_T1);
    k_final<<<KC, 256, 0, stream>>>(ws + O_RSUM, ws + O_RXSQ, ws + O_MUSQ,
                                    ws + O_T1, out);
}

// Round 5
// 670.636 us; speedup vs baseline: 2.3126x; 2.3126x over previous
//
#include <hip/hip_runtime.h>
#include <math.h>

#define N_ROWS 16384
#define DIM 1024
#define KC 32
#define LF 16
#define LOG2PI_F 1.8378770664093453f
#define Y_STRIDE 560

typedef __attribute__((ext_vector_type(8))) short bf16x8;
typedef __attribute__((ext_vector_type(4))) float f32x4;

// ---- workspace layout (float offsets) ----
#define O_XH    0               // bf16 [16384][1024] hi
#define O_XL    8388608         // bf16 [16384][1024] lo; ALIASED as RQt [512][16384] bf16 after G1
#define O_RQT   O_XL
#define O_XBT   16777216        // bf16 [1024][16384] (transpose of xh)
#define O_Y     25165824        // fp32 [16384][560], cols 0..543 used; ALIASED as SIAZ [16][1024][512] after epiE
#define O_SIAZ  O_Y
#define O_SQ    34340864        // fp32 [16384][32]
#define O_R     34865152        // fp32 [16384][32]
#define O_WETH  35389440        // bf16 [544][1024]: rows 0..511 B=iD*A (k*16+l), 512..543 iD*MU  (hi)
#define O_WETL  35667968        // bf16 [544][1024] (lo)
#define O_AQT   35946496        // bf16 [512][1024]: A (k*16+l)
#define O_ID    36208640        // fp32 [32][1024] iD
#define O_SIAI  36241408        // fp32 [1024][512]
#define O_LMAT  36765696
#define O_M0    36773888
#define O_IL    36782080
#define O_INVM  36790272
#define O_GM    36798464
#define O_IG    36806656
#define O_CB    36814848        // [32][16]
#define O_CA    36815360        // [32][16]
#define O_CONST 36815872
#define O_SLD   36815904
#define O_LDET  36815936
#define O_PIK   36815968
#define O_CK    36816000
#define O_MUSQ  36816032
// zeroed block
#define O_MUACC 36816064        // [32][1024]
#define O_SUMRQ 36848832        // [512]
#define O_RSUM  36849344        // [32]
#define O_RXSQ  36849376        // [32]
#define O_T1    36849408        // [32]
#define ZERO_START O_MUACC
#define ZERO_COUNT 33376
#define O_XSQ   36849440        // fp32 [16384] (fully written by k_sq)

// d_out layout
#define OU_MU 0
#define OU_A  32768
#define OU_LD 557056
#define OU_PI 589824

__device__ __forceinline__ ushort f2bf(float f) {
    union { float f; unsigned u; } v; v.f = f;
    unsigned u = v.u;
    return (ushort)((u + 0x7FFFu + ((u >> 16) & 1u)) >> 16);
}
__device__ __forceinline__ float bf2f(ushort b) {
    union { unsigned u; float f; } v; v.u = ((unsigned)b) << 16;
    return v.f;
}

__device__ __forceinline__ float blockReduce256(float v, float* red) {
    int tid = threadIdx.x;
    red[tid] = v; __syncthreads();
    for (int s = 128; s > 0; s >>= 1) {
        if (tid < s) red[tid] += red[tid + s];
        __syncthreads();
    }
    float r = red[0]; __syncthreads();
    return r;
}

// ---------------- conv: x -> xh, xl (split bf16), xbT ----------------
__global__ __launch_bounds__(256) void k_conv(const float* __restrict__ x,
    float* __restrict__ ws)
{
    __shared__ ushort tile[64][66];
    int tid = threadIdx.x;
    int n0 = blockIdx.x * 64;
    int row = tid >> 2, seg = tid & 3;
    ushort* xh  = (ushort*)(ws + O_XH);
    ushort* xl  = (ushort*)(ws + O_XL);
    ushort* xbT = (ushort*)(ws + O_XBT);

    for (int c0 = 0; c0 < DIM; c0 += 64) {
        float4 f[4];
        #pragma unroll
        for (int t = 0; t < 4; t++)
            f[t] = *(const float4*)&x[(size_t)(n0 + row)*DIM + c0 + seg*16 + t*4];
        union { ushort u[8]; uint4 v; } ha, hb, la, lb;
        ushort hi16[16];
        #pragma unroll
        for (int e = 0; e < 16; e++) {
            float v = ((const float*)&f[e >> 2])[e & 3];
            ushort h = f2bf(v);
            hi16[e] = h;
            ushort lo = f2bf(v - bf2f(h));
            if (e < 8) { ha.u[e] = h; la.u[e] = lo; }
            else       { hb.u[e-8] = h; lb.u[e-8] = lo; }
        }
        size_t o = (size_t)(n0 + row)*DIM + c0 + seg*16;
        *(uint4*)&xh[o] = ha.v;  *(uint4*)&xh[o + 8] = hb.v;
        *(uint4*)&xl[o] = la.v;  *(uint4*)&xl[o + 8] = lb.v;
        #pragma unroll
        for (int e = 0; e < 16; e++) tile[seg*16 + e][row] = hi16[e];
        __syncthreads();
        int cl = tid >> 2, nseg = tid & 3;
        union { ushort u[8]; uint4 v; } ta, tb;
        #pragma unroll
        for (int e = 0; e < 8; e++) {
            ta.u[e] = tile[cl][nseg*16 + e];
            tb.u[e] = tile[cl][nseg*16 + 8 + e];
        }
        size_t ot = (size_t)(c0 + cl)*N_ROWS + n0 + nseg*16;
        *(uint4*)&xbT[ot] = ta.v; *(uint4*)&xbT[ot + 8] = tb.v;
        __syncthreads();
    }
}

// ---------------- prep: pack split bf16 operands, per-k small matrices ----------------
__global__ __launch_bounds__(256) void k_prep(
    const float* __restrict__ MU, const float* __restrict__ A,
    const float* __restrict__ logD, const float* __restrict__ PIl,
    float* __restrict__ ws)
{
    int k = blockIdx.x, tid = threadIdx.x;
    __shared__ float red[256];
    ushort* Weth = (ushort*)(ws + O_WETH);
    ushort* Wetl = (ushort*)(ws + O_WETL);
    ushort* Aqt  = (ushort*)(ws + O_AQT);
    float* iDb = ws + O_ID;

    float cb[LF];
    #pragma unroll
    for (int l = 0; l < LF; l++) cb[l] = 0.f;
    float cst = 0.f, sl = 0.f;

    for (int dd = tid; dd < DIM; dd += 256) {
        float ld  = logD[k*DIM + dd];
        float idv = expf(-ld);
        float mu  = MU[k*DIM + dd];
        cst += idv*mu*mu;
        sl  += ld;
        iDb[(size_t)k*DIM + dd] = idv;
        const float* arow = A + (size_t)(k*DIM + dd)*LF;
        #pragma unroll
        for (int l = 0; l < LF; l++) {
            float a = arow[l];
            float b = idv*a;
            ushort h = f2bf(b);
            Weth[(size_t)(k*LF + l)*DIM + dd] = h;
            Wetl[(size_t)(k*LF + l)*DIM + dd] = f2bf(b - bf2f(h));
            Aqt[(size_t)(k*LF + l)*DIM + dd] = f2bf(a);
            cb[l] += mu*b;
        }
        float cmu = idv*mu;
        ushort hm = f2bf(cmu);
        Weth[(size_t)(512 + k)*DIM + dd] = hm;
        Wetl[(size_t)(512 + k)*DIM + dd] = f2bf(cmu - bf2f(hm));
    }

    for (int l = 0; l < LF; l++) {
        float t = blockReduce256(cb[l], red);
        if (tid == 0) ws[O_CB + k*LF + l] = t;
    }
    {
        float t = blockReduce256(cst, red);
        if (tid == 0) ws[O_CONST + k] = t;
        t = blockReduce256(sl, red);
        if (tid == 0) ws[O_SLD + k] = t;
    }
    if (tid == 0) {
        float mx = -1e30f;
        for (int j = 0; j < KC; j++) mx = fmaxf(mx, PIl[j]);
        float s = 0.f;
        for (int j = 0; j < KC; j++) s += expf(PIl[j] - mx);
        ws[O_PIK + k] = expf(PIl[k] - mx) / s;
    }
    __syncthreads();

    int i = tid >> 4, j = tid & 15;
    float sL = 0.f, sM = 0.f;
    for (int dd = 0; dd < DIM; dd++) {
        const float* arow = A + (size_t)(k*DIM + dd)*LF;
        float ai = arow[i], aj = arow[j];
        float idv = iDb[(size_t)k*DIM + dd];
        sL += ai*aj*idv;
        sM += ai*aj;
    }
    float s2 = expf(logD[k*DIM]);
    ws[O_LMAT + k*256 + tid] = sL + (i == j ? 1.f : 0.f);
    ws[O_M0   + k*256 + tid] = sM + (i == j ? s2  : 0.f);
}

// ---------------- batched 16x16 inversion ----------------
__global__ __launch_bounds__(256) void k_inv16(const float* __restrict__ src,
    float* __restrict__ dst, float* __restrict__ ldet)
{
    __shared__ float M[16][33];
    __shared__ float fac[16];
    __shared__ int spv;
    __shared__ float sld;
    int m = blockIdx.x, tid = threadIdx.x;

    for (int idx = tid; idx < 16*33; idx += 256) {
        int i = idx/33, c = idx%33;
        M[i][c] = (c < 16) ? src[m*256 + i*16 + c]
                           : (c < 32 ? ((i == c-16) ? 1.f : 0.f) : 0.f);
    }
    if (tid == 0) sld = 0.f;
    __syncthreads();

    for (int j = 0; j < 16; j++) {
        if (tid == 0) {
            int p = j; float best = fabsf(M[j][j]);
            for (int i2 = j+1; i2 < 16; i2++) {
                float a = fabsf(M[i2][j]);
                if (a > best) { best = a; p = i2; }
            }
            spv = p;
            sld += logf(fabsf(M[p][j]));
        }
        __syncthreads();
        int p = spv;
        if (p != j && tid < 33) { float t = M[j][tid]; M[j][tid] = M[p][tid]; M[p][tid] = t; }
        __syncthreads();
        float pv = M[j][j];
        __syncthreads();
        if (tid < 33) M[j][tid] = M[j][tid] / pv;
        __syncthreads();
        if (tid < 16) fac[tid] = M[tid][j];
        __syncthreads();
        for (int idx = tid; idx < 16*33; idx += 256) {
            int i2 = idx/33, c = idx%33;
            if (i2 != j) M[i2][c] -= fac[i2]*M[j][c];
        }
        __syncthreads();
    }
    {
        int i = tid >> 4, c = tid & 15;
        dst[m*256 + tid] = M[i][16 + c];
    }
    if (ldet != nullptr && tid == 0) ldet[m] = sld;
}

__global__ void k_prep2(float* __restrict__ ws)
{
    int k = threadIdx.x;
    if (k < KC) {
        ws[O_CK + k] = ws[O_PIK + k]
            - 0.5f*((float)DIM*LOG2PI_F + ws[O_LDET + k] + ws[O_SLD + k] + ws[O_CONST + k]);
    }
}

// ---------------- SQ[n][k] = sum_d x^2 * iD  (exact fp32), xsq ----------------
__global__ __launch_bounds__(256) void k_sq(const float* __restrict__ x,
    const float* __restrict__ iD, float* __restrict__ SQ, float* __restrict__ xsq)
{
    __shared__ float xs[32][65];
    __shared__ float ds[32][65];
    int tid = threadIdx.x;
    int n0 = blockIdx.x * 32;
    int r = tid & 31, ks = (tid >> 5) * 4;
    int srow = tid >> 3, sc = (tid & 7) * 8;
    float acc[4] = {0.f, 0.f, 0.f, 0.f};
    float xsa = 0.f;

    for (int d0 = 0; d0 < DIM; d0 += 64) {
        __syncthreads();
        #pragma unroll
        for (int u = 0; u < 8; u += 4) {
            float4 a = *(const float4*)&x[(size_t)(n0 + srow)*DIM + d0 + sc + u];
            xs[srow][sc+u+0] = a.x*a.x; xs[srow][sc+u+1] = a.y*a.y;
            xs[srow][sc+u+2] = a.z*a.z; xs[srow][sc+u+3] = a.w*a.w;
            float4 b = *(const float4*)&iD[(size_t)srow*DIM + d0 + sc + u];
            ds[srow][sc+u+0] = b.x; ds[srow][sc+u+1] = b.y;
            ds[srow][sc+u+2] = b.z; ds[srow][sc+u+3] = b.w;
        }
        __syncthreads();
        for (int d = 0; d < 64; d++) {
            float xv = xs[r][d];
            if (ks == 0) xsa += xv;
            acc[0] += xv*ds[ks+0][d];
            acc[1] += xv*ds[ks+1][d];
            acc[2] += xv*ds[ks+2][d];
            acc[3] += xv*ds[ks+3][d];
        }
    }
    #pragma unroll
    for (int j = 0; j < 4; j++)
        SQ[(size_t)(n0 + r)*KC + ks + j] = acc[j];
    if (ks == 0) xsq[n0 + r] = xsa;
}

// ---------------- 128x128 bf16 MFMA GEMM core ----------------
__device__ __forceinline__ void gemm128_core(
    const ushort* __restrict__ Ab, const ushort* __restrict__ Bb,
    size_t Ka, size_t Kb, int m0, int n0, int kbeg, int kend,
    f32x4 acc[4][4])
{
    __shared__ __align__(16) ushort As[2*5120];   // [2][128][40]
    __shared__ __align__(16) ushort Bs[2*5120];
    int tid = threadIdx.x;
    int ar0 = tid >> 2,          ac0 = (tid & 3) * 8;
    int ar1 = (tid + 256) >> 2,  ac1 = ac0;
    int lane = tid & 63, w = tid >> 6;
    int wm = w >> 1, wn = w & 1;
    int lr = lane & 15, lg = lane >> 4;

    float4 ra0, ra1, rb0, rb1;
    auto LOADT = [&](int kt) {
        ra0 = *(const float4*)&Ab[(size_t)(m0 + ar0)*Ka + kt + ac0];
        ra1 = *(const float4*)&Ab[(size_t)(m0 + ar1)*Ka + kt + ac1];
        rb0 = *(const float4*)&Bb[(size_t)(n0 + ar0)*Kb + kt + ac0];
        rb1 = *(const float4*)&Bb[(size_t)(n0 + ar1)*Kb + kt + ac1];
    };
    auto STORET = [&](int buf) {
        *(float4*)&As[buf*5120 + ar0*40 + ac0] = ra0;
        *(float4*)&As[buf*5120 + ar1*40 + ac1] = ra1;
        *(float4*)&Bs[buf*5120 + ar0*40 + ac0] = rb0;
        *(float4*)&Bs[buf*5120 + ar1*40 + ac1] = rb1;
    };

    LOADT(kbeg);
    STORET(0);
    __syncthreads();
    int cur = 0;
    for (int kt = kbeg; kt < kend; kt += 32) {
        bool more = (kt + 32 < kend);
        if (more) LOADT(kt + 32);
        bf16x8 af[4], bfr[4];
        #pragma unroll
        for (int mi = 0; mi < 4; mi++)
            af[mi] = *(bf16x8*)&As[cur*5120 + (wm*64 + mi*16 + lr)*40 + lg*8];
        #pragma unroll
        for (int ni = 0; ni < 4; ni++)
            bfr[ni] = *(bf16x8*)&Bs[cur*5120 + (wn*64 + ni*16 + lr)*40 + lg*8];
        #pragma unroll
        for (int mi = 0; mi < 4; mi++)
            #pragma unroll
            for (int ni = 0; ni < 4; ni++)
                acc[mi][ni] = __builtin_amdgcn_mfma_f32_16x16x32_bf16(
                    af[mi], bfr[ni], acc[mi][ni], 0, 0, 0);
        if (more) STORET(cur ^ 1);
        cur ^= 1;
        __syncthreads();
    }
}

// ---------------- G1: Y (fp32) = split(X) @ split(Wet)^T ----------------
__global__ __launch_bounds__(256) void k_gemm_y(
    const ushort* __restrict__ XH, const ushort* __restrict__ XL,
    const ushort* __restrict__ WH, const ushort* __restrict__ WL,
    float* __restrict__ Y)
{
    int m0 = blockIdx.x * 128, n0 = blockIdx.y * 128;
    f32x4 acc[4][4];
    #pragma unroll
    for (int a = 0; a < 4; a++)
        #pragma unroll
        for (int b = 0; b < 4; b++) acc[a][b] = (f32x4)0.f;
    gemm128_core(XH, WH, DIM, DIM, m0, n0, 0, DIM, acc);
    gemm128_core(XH, WL, DIM, DIM, m0, n0, 0, DIM, acc);
    gemm128_core(XL, WH, DIM, DIM, m0, n0, 0, DIM, acc);
    int lane = threadIdx.x & 63, w = threadIdx.x >> 6;
    int wm = w >> 1, wn = w & 1, lr = lane & 15, lg = lane >> 4;
    #pragma unroll
    for (int mi = 0; mi < 4; mi++)
        #pragma unroll
        for (int ni = 0; ni < 4; ni++) {
            int c = n0 + wn*64 + ni*16 + lr;
            if (c < 544) {
                #pragma unroll
                for (int j = 0; j < 4; j++)
                    Y[(size_t)(m0 + wm*64 + mi*16 + lg*4 + j)*Y_STRIDE + c]
                        = acc[mi][ni][j];
            }
        }
}

// ---------------- G2: RQt (bf16, transposed) = r*(Xb@Aqt^T - cA), sumRQ ----------------
__global__ __launch_bounds__(256) void k_gemm_rq(
    const ushort* __restrict__ Ab, const ushort* __restrict__ Bb,
    const float* __restrict__ rr, const float* __restrict__ cA,
    ushort* __restrict__ RQt, float* __restrict__ sumRQ)
{
    __shared__ float rs[128][32];
    __shared__ float cAs[128];
    int tid = threadIdx.x;
    int m0 = blockIdx.x * 128, n0 = blockIdx.y * 128;
    for (int i = tid; i < 128*8; i += 256) {
        int row = i >> 3, kq = (i & 7) * 4;
        *(float4*)&rs[row][kq] = *(const float4*)&rr[(size_t)(m0 + row)*KC + kq];
    }
    if (tid < 128) cAs[tid] = cA[n0 + tid];
    f32x4 acc[4][4];
    #pragma unroll
    for (int a = 0; a < 4; a++)
        #pragma unroll
        for (int b = 0; b < 4; b++) acc[a][b] = (f32x4)0.f;
    gemm128_core(Ab, Bb, DIM, DIM, m0, n0, 0, DIM, acc);
    int lane = tid & 63, w = tid >> 6;
    int wm = w >> 1, wn = w & 1, lr = lane & 15, lg = lane >> 4;
    float colsum[4] = {0.f, 0.f, 0.f, 0.f};
    #pragma unroll
    for (int ni = 0; ni < 4; ni++) {
        int colL = wn*64 + ni*16 + lr;
        int kk = (n0 + colL) >> 4;
        float ca = cAs[colL];
        #pragma unroll
        for (int mi = 0; mi < 4; mi++) {
            int row0 = wm*64 + mi*16 + lg*4;
            union { ushort u[4]; uint2 v; } pk;
            #pragma unroll
            for (int j = 0; j < 4; j++) {
                float rv = rs[row0 + j][kk];
                float q = acc[mi][ni][j] - ca;
                float rq = q * rv;
                colsum[ni] += rq;
                pk.u[j] = f2bf(rq);
            }
            *(uint2*)&RQt[(size_t)(n0 + colL)*N_ROWS + m0 + row0] = pk.v;
        }
    }
    #pragma unroll
    for (int ni = 0; ni < 4; ni++) {
        float v = colsum[ni];
        v += __shfl_xor(v, 16);
        v += __shfl_xor(v, 32);
        if (lg == 0) atomicAdd(&sumRQ[n0 + wn*64 + ni*16 + lr], v);
    }
}

// ---------------- G3: SiAz[z] = XbT @ RQt^T (K-chunk) ----------------
__global__ __launch_bounds__(256) void k_gemm_sz(
    const ushort* __restrict__ Ab, const ushort* __restrict__ Bb,
    float* __restrict__ SiAz)
{
    int m0 = blockIdx.x * 128, n0 = blockIdx.y * 128;
    int kbeg = blockIdx.z * 1024, kend = kbeg + 1024;
    f32x4 acc[4][4];
    #pragma unroll
    for (int a = 0; a < 4; a++)
        #pragma unroll
        for (int b = 0; b < 4; b++) acc[a][b] = (f32x4)0.f;
    gemm128_core(Ab, Bb, N_ROWS, N_ROWS, m0, n0, kbeg, kend, acc);
    float* dst = SiAz + (size_t)blockIdx.z * DIM * 512;
    int lane = threadIdx.x & 63, w = threadIdx.x >> 6;
    int wm = w >> 1, wn = w & 1, lr = lane & 15, lg = lane >> 4;
    #pragma unroll
    for (int mi = 0; mi < 4; mi++)
        #pragma unroll
        for (int ni = 0; ni < 4; ni++) {
            int c = n0 + wn*64 + ni*16 + lr;
            #pragma unroll
            for (int j = 0; j < 4; j++)
                dst[(size_t)(m0 + wm*64 + mi*16 + lg*4 + j)*512 + c] = acc[mi][ni][j];
        }
}

__global__ __launch_bounds__(256) void k_sired(const float* __restrict__ SiAz,
    float* __restrict__ SiAi)
{
    int i = blockIdx.x * 256 + threadIdx.x;
    float s = 0.f;
    #pragma unroll
    for (int z = 0; z < 16; z++) s += SiAz[(size_t)z*DIM*512 + i];
    SiAi[i] = s;
}

// ---------------- E-step epilogue: responsibilities ----------------
__global__ __launch_bounds__(256) void k_epiE(const float* __restrict__ Y,
    const float* __restrict__ SQ, const float* __restrict__ iL,
    const float* __restrict__ cB, const float* __restrict__ Ck,
    const float* __restrict__ xsq,
    float* __restrict__ rr, float* __restrict__ rsum, float* __restrict__ rxsq)
{
    __shared__ float iLs[32*257];
    __shared__ float yr[8*Y_STRIDE];
    __shared__ float cBs[512];
    __shared__ float rs_s[32], rx_s[32];
    int tid = threadIdx.x;
    int n0 = blockIdx.x*8;

    for (int idx = tid; idx < 8192; idx += 256)
        iLs[(idx >> 8)*257 + (idx & 255)] = iL[idx];
    for (int idx = tid; idx < 512; idx += 256) cBs[idx] = cB[idx];
    for (int idx = tid; idx < 8*Y_STRIDE; idx += 256)
        yr[idx] = Y[(size_t)n0*Y_STRIDE + idx];
    if (tid < 32) { rs_s[tid] = 0.f; rx_s[tid] = 0.f; }
    __syncthreads();

    int row = tid >> 5, k = tid & 31;
    const float* yrow = yr + row*Y_STRIDE;
    float y[16];
    #pragma unroll
    for (int j = 0; j < 16; j++) y[j] = yrow[k*16 + j] - cBs[k*16 + j];
    float t2 = 0.f;
    for (int i2 = 0; i2 < 16; i2++) {
        float ti = 0.f;
        const float* ilr = iLs + k*257 + i2*16;
        #pragma unroll
        for (int j = 0; j < 16; j++) ti += ilr[j]*y[j];
        t2 += y[i2]*ti;
    }
    float cross = yrow[512 + k];
    float sq    = SQ[(size_t)(n0 + row)*KC + k];
    float cll = Ck[k] + cross - 0.5f*sq + 0.5f*t2;

    float mx = cll;
    #pragma unroll
    for (int m = 16; m >= 1; m >>= 1) mx = fmaxf(mx, __shfl_xor(mx, m, 32));
    float e = __expf(cll - mx);
    float ssum = e;
    #pragma unroll
    for (int m = 16; m >= 1; m >>= 1) ssum += __shfl_xor(ssum, m, 32);
    float rv = e / ssum;

    rr[(size_t)(n0 + row)*KC + k] = rv;
    atomicAdd(&rs_s[k], rv);
    atomicAdd(&rx_s[k], rv*xsq[n0 + row]);
    __syncthreads();
    if (tid < 32) {
        atomicAdd(&rsum[tid], rs_s[tid]);
        atomicAdd(&rxsq[tid], rx_s[tid]);
    }
}

// ---------------- mu accumulation: muacc = r^T x ----------------
__global__ __launch_bounds__(256) void k_mu(const float* __restrict__ x,
    const float* __restrict__ rr, float* __restrict__ muacc)
{
    __shared__ float rl[8][32];
    int tid = threadIdx.x;
    int d0 = blockIdx.x*128;
    int n0 = blockIdx.y*512;
    int dd = d0 + (tid & 127);
    int kg = (tid >> 7)*16;
    float acc[16];
    #pragma unroll
    for (int j = 0; j < 16; j++) acc[j] = 0.f;

    for (int nb = 0; nb < 512; nb += 8) {
        __syncthreads();
        rl[tid >> 5][tid & 31] = rr[(size_t)(n0 + nb + (tid >> 5))*KC + (tid & 31)];
        __syncthreads();
        for (int r2 = 0; r2 < 8; r2++) {
            float xv = x[(size_t)(n0 + nb + r2)*DIM + dd];
            #pragma unroll
            for (int j = 0; j < 16; j++) acc[j] += rl[r2][kg + j]*xv;
        }
    }
    #pragma unroll
    for (int j = 0; j < 16; j++)
        atomicAdd(&muacc[(size_t)(kg + j)*DIM + dd], acc[j]);
}

// ---------------- finalize mu, cA, musq ----------------
__global__ __launch_bounds__(256) void k_mufin(const float* __restrict__ muacc,
    const float* __restrict__ rsum, const float* __restrict__ A,
    float* __restrict__ out_mu, float* __restrict__ cA, float* __restrict__ musq)
{
    __shared__ float red[256];
    int k = blockIdx.x, tid = threadIdx.x;
    float rs = rsum[k];
    float ca[16];
    #pragma unroll
    for (int l = 0; l < 16; l++) ca[l] = 0.f;
    float msq = 0.f;
    for (int dd = tid; dd < DIM; dd += 256) {
        float m = muacc[(size_t)k*DIM + dd] / rs;
        out_mu[(size_t)k*DIM + dd] = m;
        msq += m*m;
        const float* arow = A + (size_t)(k*DIM + dd)*LF;
        #pragma unroll
        for (int l = 0; l < 16; l++) ca[l] += m*arow[l];
    }
    for (int l = 0; l < 16; l++) {
        float t = blockReduce256(ca[l], red);
        if (tid == 0) cA[k*16 + l] = t;
    }
    float t = blockReduce256(msq, red);
    if (tid == 0) musq[k] = t;
}

// ---------------- ATSiAi and Gm ----------------
__global__ __launch_bounds__(256) void k_ats(const float* __restrict__ A,
    const float* __restrict__ logD, const float* __restrict__ SiAi,
    const float* __restrict__ cA, const float* __restrict__ sumRQ,
    const float* __restrict__ rsum, const float* __restrict__ invM,
    float* __restrict__ Gm)
{
    __shared__ float atsl[256];
    int k = blockIdx.x, tid = threadIdx.x, i = tid >> 4, j = tid & 15;
    float s = 0.f;
    for (int dd = 0; dd < DIM; dd++) {
        s += A[((size_t)k*DIM + dd)*LF + i] * SiAi[(size_t)dd*512 + k*16 + j];
    }
    float av = (s - cA[k*16 + i]*sumRQ[k*16 + j]) / rsum[k];
    atsl[tid] = av;
    __syncthreads();
    float s2 = expf(logD[k*DIM]);
    float g = (i == j) ? s2 : 0.f;
    #pragma unroll
    for (int m = 0; m < 16; m++) g += invM[k*256 + i*16 + m]*atsl[m*16 + j];
    Gm[k*256 + tid] = g;
}

// ---------------- A_new rows + t1 ----------------
__global__ __launch_bounds__(256) void k_anew(const float* __restrict__ SiAi,
    const float* __restrict__ mu_out, const float* __restrict__ sumRQ,
    const float* __restrict__ rsum, const float* __restrict__ iG,
    const float* __restrict__ invM, float* __restrict__ outA, float* __restrict__ t1)
{
    __shared__ float iGs[256], iMs[256];
    __shared__ float red[256];
    int k = blockIdx.x, tid = threadIdx.x;
    int dd = blockIdx.y*256 + tid;
    iGs[tid] = iG[k*256 + tid];
    iMs[tid] = invM[k*256 + tid];
    __syncthreads();
    float rs = rsum[k];
    float mv = mu_out[(size_t)k*DIM + dd];
    float sr[16];
    #pragma unroll
    for (int j = 0; j < 16; j++)
        sr[j] = (SiAi[(size_t)dd*512 + k*16 + j] - mv*sumRQ[k*16 + j]) / rs;
    float t1p = 0.f;
    float an[16];
    #pragma unroll
    for (int j = 0; j < 16; j++) {
        float a = 0.f, b = 0.f;
        #pragma unroll
        for (int m = 0; m < 16; m++) {
            a += sr[m]*iGs[m*16 + j];
            b += sr[m]*iMs[m*16 + j];
        }
        an[j] = a;
        t1p += a*b;
    }
    #pragma unroll
    for (int j = 0; j < 16; j += 4)
        *(float4*)&outA[((size_t)k*DIM + dd)*LF + j] =
            make_float4(an[j], an[j+1], an[j+2], an[j+3]);
    red[tid] = t1p; __syncthreads();
    for (int s = 128; s > 0; s >>= 1) {
        if (tid < s) red[tid] += red[tid + s];
        __syncthreads();
    }
    if (tid == 0) atomicAdd(&t1[k], red[0]);
}

// ---------------- final: log_D_new, PI_logits_new ----------------
__global__ __launch_bounds__(256) void k_final(const float* __restrict__ rsum,
    const float* __restrict__ rxsq, const float* __restrict__ musq,
    const float* __restrict__ t1, float* __restrict__ out)
{
    int k = blockIdx.x, tid = threadIdx.x;
    float rs = rsum[k];
    float ts = (rxsq[k] - rs*musq[k]) / rs;
    float sig = (ts - t1[k]) / (float)DIM;
    float ld = logf(sig);
    for (int dd = tid; dd < DIM; dd += 256)
        out[OU_LD + (size_t)k*DIM + dd] = ld;
    if (tid == 0) {
        float s = 0.f;
        for (int j = 0; j < KC; j++) s += rsum[j];
        out[OU_PI + k] = logf(rs / s);
    }
}

extern "C" void kernel_launch(void* const* d_in, const int* in_sizes, int n_in,
                              void* d_out, int out_size, void* d_ws, size_t ws_size,
                              hipStream_t stream) {
    const float* x    = (const float*)d_in[0];
    const float* MU   = (const float*)d_in[1];
    const float* A    = (const float*)d_in[2];
    const float* logD = (const float*)d_in[3];
    const float* PIl  = (const float*)d_in[4];
    float* out = (float*)d_out;
    float* ws  = (float*)d_ws;

    hipMemsetAsync(ws + ZERO_START, 0, (size_t)ZERO_COUNT*sizeof(float), stream);

    k_conv<<<N_ROWS/64, 256, 0, stream>>>(x, ws);
    k_prep<<<KC, 256, 0, stream>>>(MU, A, logD, PIl, ws);
    k_inv16<<<KC, 256, 0, stream>>>(ws + O_LMAT, ws + O_IL, ws + O_LDET);
    k_inv16<<<KC, 256, 0, stream>>>(ws + O_M0, ws + O_INVM, nullptr);
    k_prep2<<<1, 32, 0, stream>>>(ws);
    k_sq<<<N_ROWS/32, 256, 0, stream>>>(x, ws + O_ID, ws + O_SQ, ws + O_XSQ);

    k_gemm_y<<<dim3(N_ROWS/128, 5), 256, 0, stream>>>(
        (const ushort*)(ws + O_XH), (const ushort*)(ws + O_XL),
        (const ushort*)(ws + O_WETH), (const ushort*)(ws + O_WETL),
        ws + O_Y);

    k_epiE<<<N_ROWS/8, 256, 0, stream>>>(ws + O_Y, ws + O_SQ, ws + O_IL,
                                         ws + O_CB, ws + O_CK, ws + O_XSQ,
                                         ws + O_R, ws + O_RSUM, ws + O_RXSQ);

    k_mu<<<dim3(8, 32), 256, 0, stream>>>(x, ws + O_R, ws + O_MUACC);
    k_mufin<<<KC, 256, 0, stream>>>(ws + O_MUACC, ws + O_RSUM, A,
                                    out + OU_MU, ws + O_CA, ws + O_MUSQ);

    k_gemm_rq<<<dim3(N_ROWS/128, 4), 256, 0, stream>>>(
        (const ushort*)(ws + O_XH), (const ushort*)(ws + O_AQT),
        ws + O_R, ws + O_CA, (ushort*)(ws + O_RQT), ws + O_SUMRQ);

    k_gemm_sz<<<dim3(8, 4, 16), 256, 0, stream>>>(
        (const ushort*)(ws + O_XBT), (const ushort*)(ws + O_RQT), ws + O_SIAZ);
    k_sired<<<DIM*512/256, 256, 0, stream>>>(ws + O_SIAZ, ws + O_SIAI);

    k_ats<<<KC, 256, 0, stream>>>(A, logD, ws + O_SIAI, ws + O_CA, ws + O_SUMRQ,
                                  ws + O_RSUM, ws + O_INVM, ws + O_GM);
    k_inv16<<<KC, 256, 0, stream>>>(ws + O_GM, ws + O_IG, nullptr);
    k_anew<<<dim3(KC, 4), 256, 0, stream>>>(ws + O_SIAI, out + OU_MU, ws + O_SUMRQ,
                                            ws + O_RSUM, ws + O_IG, ws + O_INVM,
                                            out + OU_A, ws + O_T1);
    k_final<<<KC, 256, 0, stream>>>(ws + O_RSUM, ws + O_RXSQ, ws + O_MUSQ,
                                    ws + O_T1, out);
}

// Round 7
// 570.389 us; speedup vs baseline: 2.7191x; 1.1758x over previous
//
#include <hip/hip_runtime.h>
#include <math.h>

#define N_ROWS 16384
#define DIM 1024
#define KC 32
#define LF 16
#define LOG2PI_F 1.8378770664093453f

typedef __attribute__((ext_vector_type(8))) short bf16x8;
typedef __attribute__((ext_vector_type(4))) float f32x4;

// ---- workspace layout (float offsets) ----
#define O_XH    0               // bf16 [16384][1024] hi(x)
#define O_XL    8388608         // bf16 [16384][1024] lo(x); ALIASED as RQt [512][16384] bf16 after G1/AUX
#define O_RQT   O_XL
#define O_X2H   16777216        // bf16 [16384][1024] bf16(x^2)
#define O_XBT   25165824        // bf16 [1024][16384] transpose of xh
#define O_Y     33554432        // fp32 [16384][512]; ALIASED as SIAZ [16][1024][512] after epiE
#define O_SIAZ  O_Y
#define O_AUX   41943040        // fp32 [16384][64]: 0..31 cross, 32..63 sq; ALIASED as SIAI [1024][512] after epiE
#define O_SIAI  O_AUX
#define O_R     42991616        // fp32 [16384][32]
#define O_WETH  43515904        // bf16 [512][1024] hi(iD*A), row k*16+l
#define O_WETL  43778048        // bf16 [512][1024] lo(iD*A)
#define O_CRH   44040192        // bf16 [32][1024] hi(iD*MU)
#define O_CRL   44056576        // bf16 [32][1024] lo(iD*MU)
#define O_IDC   44072960        // bf16 [32][1024] bf16(iD)
#define O_AQT   44089344        // bf16 [512][1024] A, row k*16+l
#define O_ID    44351488        // fp32 [32][1024] iD
#define O_LMAT  44384256
#define O_M0    44392448
#define O_IL    44400640
#define O_INVM  44408832
#define O_GM    44417024
#define O_IG    44425216
#define O_CB    44433408        // [32][16]
#define O_CA    44433920        // [32][16]
#define O_CONST 44434432
#define O_SLD   44434464
#define O_LDET  44434496
#define O_PIK   44434528
#define O_CK    44434560
#define O_MUSQ  44434592
// zeroed block
#define O_MUACC 44434624        // [32][1024]
#define O_SUMRQ 44467392        // [512]
#define O_RSUM  44467904        // [32]
#define O_RXSQ  44467936        // [32]
#define O_T1    44467968        // [32]
#define O_ATS   44468000        // [32][256]
#define ZERO_START O_MUACC
#define ZERO_COUNT 41568
#define O_XSQ   44476192        // fp32 [16384] (fully written by k_conv)

// d_out layout
#define OU_MU 0
#define OU_A  32768
#define OU_LD 557056
#define OU_PI 589824

__device__ __forceinline__ ushort f2bf(float f) {
    union { float f; unsigned u; } v; v.f = f;
    unsigned u = v.u;
    return (ushort)((u + 0x7FFFu + ((u >> 16) & 1u)) >> 16);
}
__device__ __forceinline__ float bf2f(ushort b) {
    union { unsigned u; float f; } v; v.u = ((unsigned)b) << 16;
    return v.f;
}

__device__ __forceinline__ float blockReduce256(float v, float* red) {
    int tid = threadIdx.x;
    red[tid] = v; __syncthreads();
    for (int s = 128; s > 0; s >>= 1) {
        if (tid < s) red[tid] += red[tid + s];
        __syncthreads();
    }
    float r = red[0]; __syncthreads();
    return r;
}

// ---------------- conv: x -> xh, xl, x2h (bf16), xbT, xsq ----------------
__global__ __launch_bounds__(256) void k_conv(const float* __restrict__ x,
    float* __restrict__ ws)
{
    __shared__ ushort tile[64][66];
    int tid = threadIdx.x;
    int n0 = blockIdx.x * 64;
    int row = tid >> 2, seg = tid & 3;
    ushort* xh  = (ushort*)(ws + O_XH);
    ushort* xl  = (ushort*)(ws + O_XL);
    ushort* x2h = (ushort*)(ws + O_X2H);
    ushort* xbT = (ushort*)(ws + O_XBT);
    float xs_acc = 0.f;

    for (int c0 = 0; c0 < DIM; c0 += 64) {
        float4 f[4];
        #pragma unroll
        for (int t = 0; t < 4; t++)
            f[t] = *(const float4*)&x[(size_t)(n0 + row)*DIM + c0 + seg*16 + t*4];
        union { ushort u[8]; uint4 v; } ha, hb, la, lb, qa, qb;
        ushort hi16[16];
        #pragma unroll
        for (int e = 0; e < 16; e++) {
            float v = ((const float*)&f[e >> 2])[e & 3];
            xs_acc += v*v;
            ushort h = f2bf(v);
            hi16[e] = h;
            ushort lo = f2bf(v - bf2f(h));
            ushort q  = f2bf(v*v);
            if (e < 8) { ha.u[e] = h; la.u[e] = lo; qa.u[e] = q; }
            else       { hb.u[e-8] = h; lb.u[e-8] = lo; qb.u[e-8] = q; }
        }
        size_t o = (size_t)(n0 + row)*DIM + c0 + seg*16;
        *(uint4*)&xh[o] = ha.v;   *(uint4*)&xh[o + 8] = hb.v;
        *(uint4*)&xl[o] = la.v;   *(uint4*)&xl[o + 8] = lb.v;
        *(uint4*)&x2h[o] = qa.v;  *(uint4*)&x2h[o + 8] = qb.v;
        #pragma unroll
        for (int e = 0; e < 16; e++) tile[seg*16 + e][row] = hi16[e];
        __syncthreads();
        int cl = tid >> 2, nseg = tid & 3;
        union { ushort u[8]; uint4 v; } ta, tb;
        #pragma unroll
        for (int e = 0; e < 8; e++) {
            ta.u[e] = tile[cl][nseg*16 + e];
            tb.u[e] = tile[cl][nseg*16 + 8 + e];
        }
        size_t ot = (size_t)(c0 + cl)*N_ROWS + n0 + nseg*16;
        *(uint4*)&xbT[ot] = ta.v; *(uint4*)&xbT[ot + 8] = tb.v;
        __syncthreads();
    }
    // exact xsq: reduce across the 4 seg-threads (consecutive lanes)
    xs_acc += __shfl_xor(xs_acc, 1);
    xs_acc += __shfl_xor(xs_acc, 2);
    if ((tid & 3) == 0) (ws + O_XSQ)[n0 + row] = xs_acc;
}

// ---------------- prep: pack bf16 operands, per-k small matrices ----------------
__global__ __launch_bounds__(256) void k_prep(
    const float* __restrict__ MU, const float* __restrict__ A,
    const float* __restrict__ logD, const float* __restrict__ PIl,
    float* __restrict__ ws)
{
    int k = blockIdx.x, tid = threadIdx.x;
    __shared__ float red[256];
    ushort* Weth = (ushort*)(ws + O_WETH);
    ushort* Wetl = (ushort*)(ws + O_WETL);
    ushort* Crh  = (ushort*)(ws + O_CRH);
    ushort* Crl  = (ushort*)(ws + O_CRL);
    ushort* Idc  = (ushort*)(ws + O_IDC);
    ushort* Aqt  = (ushort*)(ws + O_AQT);
    float* iDb = ws + O_ID;

    float cb[LF];
    #pragma unroll
    for (int l = 0; l < LF; l++) cb[l] = 0.f;
    float cst = 0.f, sl = 0.f;

    for (int dd = tid; dd < DIM; dd += 256) {
        float ld  = logD[k*DIM + dd];
        float idv = expf(-ld);
        float mu  = MU[k*DIM + dd];
        cst += idv*mu*mu;
        sl  += ld;
        iDb[(size_t)k*DIM + dd] = idv;
        const float* arow = A + (size_t)(k*DIM + dd)*LF;
        #pragma unroll
        for (int l = 0; l < LF; l++) {
            float a = arow[l];
            float b = idv*a;
            ushort h = f2bf(b);
            Weth[(size_t)(k*LF + l)*DIM + dd] = h;
            Wetl[(size_t)(k*LF + l)*DIM + dd] = f2bf(b - bf2f(h));
            Aqt[(size_t)(k*LF + l)*DIM + dd] = f2bf(a);
            cb[l] += mu*b;
        }
        float cmu = idv*mu;
        ushort hm = f2bf(cmu);
        Crh[(size_t)k*DIM + dd] = hm;
        Crl[(size_t)k*DIM + dd] = f2bf(cmu - bf2f(hm));
        Idc[(size_t)k*DIM + dd] = f2bf(idv);
    }

    for (int l = 0; l < LF; l++) {
        float t = blockReduce256(cb[l], red);
        if (tid == 0) ws[O_CB + k*LF + l] = t;
    }
    {
        float t = blockReduce256(cst, red);
        if (tid == 0) ws[O_CONST + k] = t;
        t = blockReduce256(sl, red);
        if (tid == 0) ws[O_SLD + k] = t;
    }
    if (tid == 0) {
        float mx = -1e30f;
        for (int j = 0; j < KC; j++) mx = fmaxf(mx, PIl[j]);
        float s = 0.f;
        for (int j = 0; j < KC; j++) s += expf(PIl[j] - mx);
        ws[O_PIK + k] = expf(PIl[k] - mx) / s;
    }
    __syncthreads();

    int i = tid >> 4, j = tid & 15;
    float sL = 0.f, sM = 0.f;
    for (int dd = 0; dd < DIM; dd++) {
        const float* arow = A + (size_t)(k*DIM + dd)*LF;
        float ai = arow[i], aj = arow[j];
        float idv = iDb[(size_t)k*DIM + dd];
        sL += ai*aj*idv;
        sM += ai*aj;
    }
    float s2 = expf(logD[k*DIM]);
    ws[O_LMAT + k*256 + tid] = sL + (i == j ? 1.f : 0.f);
    ws[O_M0   + k*256 + tid] = sM + (i == j ? s2  : 0.f);
}

// ---------------- batched 16x16 inversion ----------------
__global__ __launch_bounds__(256) void k_inv16(const float* __restrict__ src,
    float* __restrict__ dst, float* __restrict__ ldet)
{
    __shared__ float M[16][33];
    __shared__ float fac[16];
    __shared__ int spv;
    __shared__ float sld;
    int m = blockIdx.x, tid = threadIdx.x;

    for (int idx = tid; idx < 16*33; idx += 256) {
        int i = idx/33, c = idx%33;
        M[i][c] = (c < 16) ? src[m*256 + i*16 + c]
                           : (c < 32 ? ((i == c-16) ? 1.f : 0.f) : 0.f);
    }
    if (tid == 0) sld = 0.f;
    __syncthreads();

    for (int j = 0; j < 16; j++) {
        if (tid == 0) {
            int p = j; float best = fabsf(M[j][j]);
            for (int i2 = j+1; i2 < 16; i2++) {
                float a = fabsf(M[i2][j]);
                if (a > best) { best = a; p = i2; }
            }
            spv = p;
            sld += logf(fabsf(M[p][j]));
        }
        __syncthreads();
        int p = spv;
        if (p != j && tid < 33) { float t = M[j][tid]; M[j][tid] = M[p][tid]; M[p][tid] = t; }
        __syncthreads();
        float pv = M[j][j];
        __syncthreads();
        if (tid < 33) M[j][tid] = M[j][tid] / pv;
        __syncthreads();
        if (tid < 16) fac[tid] = M[tid][j];
        __syncthreads();
        for (int idx = tid; idx < 16*33; idx += 256) {
            int i2 = idx/33, c = idx%33;
            if (i2 != j) M[i2][c] -= fac[i2]*M[j][c];
        }
        __syncthreads();
    }
    {
        int i = tid >> 4, c = tid & 15;
        dst[m*256 + tid] = M[i][16 + c];
    }
    if (ldet != nullptr && tid == 0) ldet[m] = sld;
}

__global__ void k_prep2(float* __restrict__ ws)
{
    int k = threadIdx.x;
    if (k < KC) {
        ws[O_CK + k] = ws[O_PIK + k]
            - 0.5f*((float)DIM*LOG2PI_F + ws[O_LDET + k] + ws[O_SLD + k] + ws[O_CONST + k]);
    }
}

// ---------------- G1 fused: Y = (xh+xl)@Wh^T + xh@Wl^T, 512 cols ----------------
__global__ __launch_bounds__(256) void k_g1f(
    const ushort* __restrict__ XH, const ushort* __restrict__ XL,
    const ushort* __restrict__ WH, const ushort* __restrict__ WL,
    float* __restrict__ Y)
{
    __shared__ __align__(16) ushort sXH[5120], sXL[5120], sWH[5120], sWL[5120]; // [128][40]
    int tid = threadIdx.x;
    int m0 = blockIdx.x*128, n0 = blockIdx.y*128;
    int ar0 = tid >> 2, ac0 = (tid & 3)*8;
    int ar1 = ar0 + 64;
    int lane = tid & 63, w = tid >> 6;
    int wm = w >> 1, wn = w & 1, lr = lane & 15, lg = lane >> 4;

    f32x4 acc[4][4];
    #pragma unroll
    for (int a = 0; a < 4; a++)
        #pragma unroll
        for (int b = 0; b < 4; b++) acc[a][b] = (f32x4)0.f;

    float4 rxh0, rxh1, rxl0, rxl1, rwh0, rwh1, rwl0, rwl1;
    auto LOADT = [&](int kt) {
        rxh0 = *(const float4*)&XH[(size_t)(m0 + ar0)*DIM + kt + ac0];
        rxh1 = *(const float4*)&XH[(size_t)(m0 + ar1)*DIM + kt + ac0];
        rxl0 = *(const float4*)&XL[(size_t)(m0 + ar0)*DIM + kt + ac0];
        rxl1 = *(const float4*)&XL[(size_t)(m0 + ar1)*DIM + kt + ac0];
        rwh0 = *(const float4*)&WH[(size_t)(n0 + ar0)*DIM + kt + ac0];
        rwh1 = *(const float4*)&WH[(size_t)(n0 + ar1)*DIM + kt + ac0];
        rwl0 = *(const float4*)&WL[(size_t)(n0 + ar0)*DIM + kt + ac0];
        rwl1 = *(const float4*)&WL[(size_t)(n0 + ar1)*DIM + kt + ac0];
    };

    LOADT(0);
    for (int kt = 0; kt < DIM; kt += 32) {
        __syncthreads();
        *(float4*)&sXH[ar0*40 + ac0] = rxh0; *(float4*)&sXH[ar1*40 + ac0] = rxh1;
        *(float4*)&sXL[ar0*40 + ac0] = rxl0; *(float4*)&sXL[ar1*40 + ac0] = rxl1;
        *(float4*)&sWH[ar0*40 + ac0] = rwh0; *(float4*)&sWH[ar1*40 + ac0] = rwh1;
        *(float4*)&sWL[ar0*40 + ac0] = rwl0; *(float4*)&sWL[ar1*40 + ac0] = rwl1;
        if (kt + 32 < DIM) LOADT(kt + 32);
        __syncthreads();

        bf16x8 bwh[4], bwl[4];
        #pragma unroll
        for (int ni = 0; ni < 4; ni++) {
            bwh[ni] = *(bf16x8*)&sWH[(wn*64 + ni*16 + lr)*40 + lg*8];
            bwl[ni] = *(bf16x8*)&sWL[(wn*64 + ni*16 + lr)*40 + lg*8];
        }
        #pragma unroll
        for (int mi = 0; mi < 4; mi++) {
            bf16x8 axh = *(bf16x8*)&sXH[(wm*64 + mi*16 + lr)*40 + lg*8];
            bf16x8 axl = *(bf16x8*)&sXL[(wm*64 + mi*16 + lr)*40 + lg*8];
            #pragma unroll
            for (int ni = 0; ni < 4; ni++) {
                acc[mi][ni] = __builtin_amdgcn_mfma_f32_16x16x32_bf16(axh, bwh[ni], acc[mi][ni], 0, 0, 0);
                acc[mi][ni] = __builtin_amdgcn_mfma_f32_16x16x32_bf16(axl, bwh[ni], acc[mi][ni], 0, 0, 0);
                acc[mi][ni] = __builtin_amdgcn_mfma_f32_16x16x32_bf16(axh, bwl[ni], acc[mi][ni], 0, 0, 0);
            }
        }
    }
    #pragma unroll
    for (int mi = 0; mi < 4; mi++)
        #pragma unroll
        for (int ni = 0; ni < 4; ni++) {
            int c = n0 + wn*64 + ni*16 + lr;
            #pragma unroll
            for (int j = 0; j < 4; j++)
                Y[(size_t)(m0 + wm*64 + mi*16 + lg*4 + j)*512 + c] = acc[mi][ni][j];
        }
}

// ---------------- AUX: cols 0..31 cross (3-pass), 32..63 sq (1-pass) ----------------
__global__ __launch_bounds__(256) void k_aux(
    const ushort* __restrict__ XH, const ushort* __restrict__ XL,
    const ushort* __restrict__ X2, const ushort* __restrict__ CRH,
    const ushort* __restrict__ CRL, const ushort* __restrict__ IDC,
    float* __restrict__ AUX)
{
    __shared__ __align__(16) ushort sXH[5120], sXL[5120], sX2[5120]; // [128][40]
    __shared__ __align__(16) ushort sB[3840];                        // [96][40]
    int tid = threadIdx.x;
    int m0 = blockIdx.x*128;
    int lane = tid & 63, w = tid >> 6;
    int lr = lane & 15, lg = lane >> 4;

    f32x4 acc[2][4];
    #pragma unroll
    for (int a = 0; a < 2; a++)
        #pragma unroll
        for (int b = 0; b < 4; b++) acc[a][b] = (f32x4)0.f;

    for (int kt = 0; kt < DIM; kt += 32) {
        __syncthreads();
        #pragma unroll
        for (int t = 0; t < 2; t++) {
            int idx = tid + t*256;
            int row = idx >> 2, seg = (idx & 3)*8;
            *(float4*)&sXH[row*40 + seg] = *(const float4*)&XH[(size_t)(m0 + row)*DIM + kt + seg];
            *(float4*)&sXL[row*40 + seg] = *(const float4*)&XL[(size_t)(m0 + row)*DIM + kt + seg];
            *(float4*)&sX2[row*40 + seg] = *(const float4*)&X2[(size_t)(m0 + row)*DIM + kt + seg];
        }
        for (int idx = tid; idx < 384; idx += 256) {
            int row = idx >> 2, seg = (idx & 3)*8;
            const ushort* src = (row < 32) ? &CRH[(size_t)row*DIM + kt + seg]
                              : (row < 64) ? &CRL[(size_t)(row-32)*DIM + kt + seg]
                                           : &IDC[(size_t)(row-64)*DIM + kt + seg];
            *(float4*)&sB[row*40 + seg] = *(const float4*)src;
        }
        __syncthreads();

        bf16x8 bch[2], bcl[2], bd[2];
        #pragma unroll
        for (int cf = 0; cf < 2; cf++) {
            bch[cf] = *(bf16x8*)&sB[(cf*16 + lr)*40 + lg*8];
            bcl[cf] = *(bf16x8*)&sB[(32 + cf*16 + lr)*40 + lg*8];
            bd[cf]  = *(bf16x8*)&sB[(64 + cf*16 + lr)*40 + lg*8];
        }
        #pragma unroll
        for (int rf = 0; rf < 2; rf++) {
            int rbase = (w*32 + rf*16 + lr)*40 + lg*8;
            bf16x8 axh = *(bf16x8*)&sXH[rbase];
            bf16x8 axl = *(bf16x8*)&sXL[rbase];
            bf16x8 ax2 = *(bf16x8*)&sX2[rbase];
            #pragma unroll
            for (int cf = 0; cf < 2; cf++) {
                acc[rf][cf] = __builtin_amdgcn_mfma_f32_16x16x32_bf16(axh, bch[cf], acc[rf][cf], 0, 0, 0);
                acc[rf][cf] = __builtin_amdgcn_mfma_f32_16x16x32_bf16(axl, bch[cf], acc[rf][cf], 0, 0, 0);
                acc[rf][cf] = __builtin_amdgcn_mfma_f32_16x16x32_bf16(axh, bcl[cf], acc[rf][cf], 0, 0, 0);
                acc[rf][2+cf] = __builtin_amdgcn_mfma_f32_16x16x32_bf16(ax2, bd[cf], acc[rf][2+cf], 0, 0, 0);
            }
        }
    }
    #pragma unroll
    for (int rf = 0; rf < 2; rf++)
        #pragma unroll
        for (int cf = 0; cf < 4; cf++) {
            int col = cf*16 + lr;
            #pragma unroll
            for (int j = 0; j < 4; j++)
                AUX[(size_t)(m0 + w*32 + rf*16 + lg*4 + j)*64 + col] = acc[rf][cf][j];
        }
}

// ---------------- 128x128 bf16 MFMA GEMM core (G2/G3) ----------------
__device__ __forceinline__ void gemm128_core(
    const ushort* __restrict__ Ab, const ushort* __restrict__ Bb,
    size_t Ka, size_t Kb, int m0, int n0, int kbeg, int kend,
    f32x4 acc[4][4])
{
    __shared__ __align__(16) ushort As[2*5120];   // [2][128][40]
    __shared__ __align__(16) ushort Bs[2*5120];
    int tid = threadIdx.x;
    int ar0 = tid >> 2,          ac0 = (tid & 3) * 8;
    int ar1 = (tid + 256) >> 2,  ac1 = ac0;
    int lane = tid & 63, w = tid >> 6;
    int wm = w >> 1, wn = w & 1;
    int lr = lane & 15, lg = lane >> 4;

    float4 ra0, ra1, rb0, rb1;
    auto LOADT = [&](int kt) {
        ra0 = *(const float4*)&Ab[(size_t)(m0 + ar0)*Ka + kt + ac0];
        ra1 = *(const float4*)&Ab[(size_t)(m0 + ar1)*Ka + kt + ac1];
        rb0 = *(const float4*)&Bb[(size_t)(n0 + ar0)*Kb + kt + ac0];
        rb1 = *(const float4*)&Bb[(size_t)(n0 + ar1)*Kb + kt + ac1];
    };
    auto STORET = [&](int buf) {
        *(float4*)&As[buf*5120 + ar0*40 + ac0] = ra0;
        *(float4*)&As[buf*5120 + ar1*40 + ac1] = ra1;
        *(float4*)&Bs[buf*5120 + ar0*40 + ac0] = rb0;
        *(float4*)&Bs[buf*5120 + ar1*40 + ac1] = rb1;
    };

    LOADT(kbeg);
    STORET(0);
    __syncthreads();
    int cur = 0;
    for (int kt = kbeg; kt < kend; kt += 32) {
        bool more = (kt + 32 < kend);
        if (more) LOADT(kt + 32);
        bf16x8 af[4], bfr[4];
        #pragma unroll
        for (int mi = 0; mi < 4; mi++)
            af[mi] = *(bf16x8*)&As[cur*5120 + (wm*64 + mi*16 + lr)*40 + lg*8];
        #pragma unroll
        for (int ni = 0; ni < 4; ni++)
            bfr[ni] = *(bf16x8*)&Bs[cur*5120 + (wn*64 + ni*16 + lr)*40 + lg*8];
        #pragma unroll
        for (int mi = 0; mi < 4; mi++)
            #pragma unroll
            for (int ni = 0; ni < 4; ni++)
                acc[mi][ni] = __builtin_amdgcn_mfma_f32_16x16x32_bf16(
                    af[mi], bfr[ni], acc[mi][ni], 0, 0, 0);
        if (more) STORET(cur ^ 1);
        cur ^= 1;
        __syncthreads();
    }
}

// ---------------- G2: RQt (bf16, transposed) = r*(Xh@Aqt^T - cA), sumRQ ----------------
__global__ __launch_bounds__(256) void k_gemm_rq(
    const ushort* __restrict__ Ab, const ushort* __restrict__ Bb,
    const float* __restrict__ rr, const float* __restrict__ cA,
    ushort* __restrict__ RQt, float* __restrict__ sumRQ)
{
    __shared__ float rs[128][32];
    __shared__ float cAs[128];
    int tid = threadIdx.x;
    int m0 = blockIdx.x * 128, n0 = blockIdx.y * 128;
    for (int i = tid; i < 128*8; i += 256) {
        int row = i >> 3, kq = (i & 7) * 4;
        *(float4*)&rs[row][kq] = *(const float4*)&rr[(size_t)(m0 + row)*KC + kq];
    }
    if (tid < 128) cAs[tid] = cA[n0 + tid];
    f32x4 acc[4][4];
    #pragma unroll
    for (int a = 0; a < 4; a++)
        #pragma unroll
        for (int b = 0; b < 4; b++) acc[a][b] = (f32x4)0.f;
    gemm128_core(Ab, Bb, DIM, DIM, m0, n0, 0, DIM, acc);
    int lane = tid & 63, w = tid >> 6;
    int wm = w >> 1, wn = w & 1, lr = lane & 15, lg = lane >> 4;
    float colsum[4] = {0.f, 0.f, 0.f, 0.f};
    #pragma unroll
    for (int ni = 0; ni < 4; ni++) {
        int colL = wn*64 + ni*16 + lr;
        int kk = (n0 + colL) >> 4;
        float ca = cAs[colL];
        #pragma unroll
        for (int mi = 0; mi < 4; mi++) {
            int row0 = wm*64 + mi*16 + lg*4;
            union { ushort u[4]; uint2 v; } pk;
            #pragma unroll
            for (int j = 0; j < 4; j++) {
                float rv = rs[row0 + j][kk];
                float q = acc[mi][ni][j] - ca;
                float rq = q * rv;
                colsum[ni] += rq;
                pk.u[j] = f2bf(rq);
            }
            *(uint2*)&RQt[(size_t)(n0 + colL)*N_ROWS + m0 + row0] = pk.v;
        }
    }
    #pragma unroll
    for (int ni = 0; ni < 4; ni++) {
        float v = colsum[ni];
        v += __shfl_xor(v, 16);
        v += __shfl_xor(v, 32);
        if (lg == 0) atomicAdd(&sumRQ[n0 + wn*64 + ni*16 + lr], v);
    }
}

// ---------------- G3: SiAz[z] = XbT @ RQt^T (K-chunk) ----------------
__global__ __launch_bounds__(256) void k_gemm_sz(
    const ushort* __restrict__ Ab, const ushort* __restrict__ Bb,
    float* __restrict__ SiAz)
{
    int m0 = blockIdx.x * 128, n0 = blockIdx.y * 128;
    int kbeg = blockIdx.z * 1024, kend = kbeg + 1024;
    f32x4 acc[4][4];
    #pragma unroll
    for (int a = 0; a < 4; a++)
        #pragma unroll
        for (int b = 0; b < 4; b++) acc[a][b] = (f32x4)0.f;
    gemm128_core(Ab, Bb, N_ROWS, N_ROWS, m0, n0, kbeg, kend, acc);
    float* dst = SiAz + (size_t)blockIdx.z * DIM * 512;
    int lane = threadIdx.x & 63, w = threadIdx.x >> 6;
    int wm = w >> 1, wn = w & 1, lr = lane & 15, lg = lane >> 4;
    #pragma unroll
    for (int mi = 0; mi < 4; mi++)
        #pragma unroll
        for (int ni = 0; ni < 4; ni++) {
            int c = n0 + wn*64 + ni*16 + lr;
            #pragma unroll
            for (int j = 0; j < 4; j++)
                dst[(size_t)(m0 + wm*64 + mi*16 + lg*4 + j)*512 + c] = acc[mi][ni][j];
        }
}

__global__ __launch_bounds__(256) void k_sired(const float* __restrict__ SiAz,
    float* __restrict__ SiAi)
{
    int i = blockIdx.x * 256 + threadIdx.x;
    float s = 0.f;
    #pragma unroll
    for (int z = 0; z < 16; z++) s += SiAz[(size_t)z*DIM*512 + i];
    SiAi[i] = s;
}

// ---------------- E-step epilogue: responsibilities (32 rows/block) ----------------
__global__ __launch_bounds__(256) void k_epiE(const float* __restrict__ Y,
    const float* __restrict__ AUX, const float* __restrict__ iL,
    const float* __restrict__ cB, const float* __restrict__ Ck,
    const float* __restrict__ xsq,
    float* __restrict__ rr, float* __restrict__ rsum, float* __restrict__ rxsq)
{
    __shared__ __align__(16) float iLs[32*260];
    __shared__ float cBs[512];
    __shared__ float rs_s[32], rx_s[32];
    int tid = threadIdx.x;
    int n0 = blockIdx.x*32;

    for (int idx = tid; idx < 8192; idx += 256)
        iLs[(idx >> 8)*260 + (idx & 255)] = iL[idx];
    for (int idx = tid; idx < 512; idx += 256) cBs[idx] = cB[idx];
    if (tid < 32) { rs_s[tid] = 0.f; rx_s[tid] = 0.f; }
    __syncthreads();

    int row8 = tid >> 5, k = tid & 31;
    const float* ilr = iLs + k*260;
    float ck = Ck[k];

    for (int it = 0; it < 4; it++) {
        int n = n0 + it*8 + row8;
        float y[16];
        #pragma unroll
        for (int j = 0; j < 16; j += 4) {
            float4 v = *(const float4*)&Y[(size_t)n*512 + k*16 + j];
            y[j] = v.x - cBs[k*16 + j];     y[j+1] = v.y - cBs[k*16 + j+1];
            y[j+2] = v.z - cBs[k*16 + j+2]; y[j+3] = v.w - cBs[k*16 + j+3];
        }
        float t2 = 0.f;
        #pragma unroll
        for (int i2 = 0; i2 < 16; i2++) {
            float4 a = *(const float4*)&ilr[i2*16];
            float4 b = *(const float4*)&ilr[i2*16 + 4];
            float4 c = *(const float4*)&ilr[i2*16 + 8];
            float4 d = *(const float4*)&ilr[i2*16 + 12];
            float ti = a.x*y[0] + a.y*y[1] + a.z*y[2] + a.w*y[3]
                     + b.x*y[4] + b.y*y[5] + b.z*y[6] + b.w*y[7]
                     + c.x*y[8] + c.y*y[9] + c.z*y[10] + c.w*y[11]
                     + d.x*y[12] + d.y*y[13] + d.z*y[14] + d.w*y[15];
            t2 += y[i2]*ti;
        }
        float cross = AUX[(size_t)n*64 + k];
        float sq    = AUX[(size_t)n*64 + 32 + k];
        float cll = ck + cross - 0.5f*sq + 0.5f*t2;

        float mx = cll;
        #pragma unroll
        for (int m = 16; m >= 1; m >>= 1) mx = fmaxf(mx, __shfl_xor(mx, m, 32));
        float e = __expf(cll - mx);
        float ssum = e;
        #pragma unroll
        for (int m = 16; m >= 1; m >>= 1) ssum += __shfl_xor(ssum, m, 32);
        float rv = e / ssum;

        rr[(size_t)n*KC + k] = rv;
        atomicAdd(&rs_s[k], rv);
        atomicAdd(&rx_s[k], rv*xsq[n]);
    }
    __syncthreads();
    if (tid < 32) {
        atomicAdd(&rsum[tid], rs_s[tid]);
        atomicAdd(&rxsq[tid], rx_s[tid]);
    }
}

// ---------------- mu accumulation: muacc = r^T x ----------------
__global__ __launch_bounds__(256) void k_mu(const float* __restrict__ x,
    const float* __restrict__ rr, float* __restrict__ muacc)
{
    __shared__ float rl[8][32];
    int tid = threadIdx.x;
    int d0 = blockIdx.x*128;
    int n0 = blockIdx.y*512;
    int dd = d0 + (tid & 127);
    int kg = (tid >> 7)*16;
    float acc[16];
    #pragma unroll
    for (int j = 0; j < 16; j++) acc[j] = 0.f;

    for (int nb = 0; nb < 512; nb += 8) {
        __syncthreads();
        rl[tid >> 5][tid & 31] = rr[(size_t)(n0 + nb + (tid >> 5))*KC + (tid & 31)];
        __syncthreads();
        for (int r2 = 0; r2 < 8; r2++) {
            float xv = x[(size_t)(n0 + nb + r2)*DIM + dd];
            #pragma unroll
            for (int j = 0; j < 16; j++) acc[j] += rl[r2][kg + j]*xv;
        }
    }
    #pragma unroll
    for (int j = 0; j < 16; j++)
        atomicAdd(&muacc[(size_t)(kg + j)*DIM + dd], acc[j]);
}

// ---------------- finalize mu, cA, musq ----------------
__global__ __launch_bounds__(256) void k_mufin(const float* __restrict__ muacc,
    const float* __restrict__ rsum, const float* __restrict__ A,
    float* __restrict__ out_mu, float* __restrict__ cA, float* __restrict__ musq)
{
    __shared__ float red[256];
    int k = blockIdx.x, tid = threadIdx.x;
    float rs = rsum[k];
    float ca[16];
    #pragma unroll
    for (int l = 0; l < 16; l++) ca[l] = 0.f;
    float msq = 0.f;
    for (int dd = tid; dd < DIM; dd += 256) {
        float m = muacc[(size_t)k*DIM + dd] / rs;
        out_mu[(size_t)k*DIM + dd] = m;
        msq += m*m;
        const float* arow = A + (size_t)(k*DIM + dd)*LF;
        #pragma unroll
        for (int l = 0; l < 16; l++) ca[l] += m*arow[l];
    }
    for (int l = 0; l < 16; l++) {
        float t = blockReduce256(ca[l], red);
        if (tid == 0) cA[k*16 + l] = t;
    }
    float t = blockReduce256(msq, red);
    if (tid == 0) musq[k] = t;
}

// ---------------- ATS partials (parallel over d-chunks) ----------------
__global__ __launch_bounds__(256) void k_ats1(const float* __restrict__ A,
    const float* __restrict__ SiAi, float* __restrict__ ATS)
{
    int k = blockIdx.x, tid = threadIdx.x, i = tid >> 4, j = tid & 15;
    int d0 = blockIdx.y*128;
    float s = 0.f;
    #pragma unroll 4
    for (int dd = d0; dd < d0 + 128; dd++)
        s += A[((size_t)k*DIM + dd)*LF + i] * SiAi[(size_t)dd*512 + k*16 + j];
    atomicAdd(&ATS[k*256 + tid], s);
}

// ---------------- Gm from ATS ----------------
__global__ __launch_bounds__(256) void k_ats2(const float* __restrict__ ATS,
    const float* __restrict__ logD, const float* __restrict__ cA,
    const float* __restrict__ sumRQ, const float* __restrict__ rsum,
    const float* __restrict__ invM, float* __restrict__ Gm)
{
    __shared__ float atsl[256];
    int k = blockIdx.x, tid = threadIdx.x, i = tid >> 4, j = tid & 15;
    float av = (ATS[k*256 + tid] - cA[k*16 + i]*sumRQ[k*16 + j]) / rsum[k];
    atsl[tid] = av;
    __syncthreads();
    float s2 = expf(logD[k*DIM]);
    float g = (i == j) ? s2 : 0.f;
    #pragma unroll
    for (int m = 0; m < 16; m++) g += invM[k*256 + i*16 + m]*atsl[m*16 + j];
    Gm[k*256 + tid] = g;
}

// ---------------- A_new rows + t1 ----------------
__global__ __launch_bounds__(256) void k_anew(const float* __restrict__ SiAi,
    const float* __restrict__ mu_out, const float* __restrict__ sumRQ,
    const float* __restrict__ rsum, const float* __restrict__ iG,
    const float* __restrict__ invM, float* __restrict__ outA, float* __restrict__ t1)
{
    __shared__ float iGs[256], iMs[256];
    __shared__ float red[256];
    int k = blockIdx.x, tid = threadIdx.x;
    int dd = blockIdx.y*256 + tid;
    iGs[tid] = iG[k*256 + tid];
    iMs[tid] = invM[k*256 + tid];
    __syncthreads();
    float rs = rsum[k];
    float mv = mu_out[(size_t)k*DIM + dd];
    float sr[16];
    #pragma unroll
    for (int j = 0; j < 16; j++)
        sr[j] = (SiAi[(size_t)dd*512 + k*16 + j] - mv*sumRQ[k*16 + j]) / rs;
    float t1p = 0.f;
    float an[16];
    #pragma unroll
    for (int j = 0; j < 16; j++) {
        float a = 0.f, b = 0.f;
        #pragma unroll
        for (int m = 0; m < 16; m++) {
            a += sr[m]*iGs[m*16 + j];
            b += sr[m]*iMs[m*16 + j];
        }
        an[j] = a;
        t1p += a*b;
    }
    #pragma unroll
    for (int j = 0; j < 16; j += 4)
        *(float4*)&outA[((size_t)k*DIM + dd)*LF + j] =
            make_float4(an[j], an[j+1], an[j+2], an[j+3]);
    red[tid] = t1p; __syncthreads();
    for (int s = 128; s > 0; s >>= 1) {
        if (tid < s) red[tid] += red[tid + s];
        __syncthreads();
    }
    if (tid == 0) atomicAdd(&t1[k], red[0]);
}

// ---------------- final: log_D_new, PI_logits_new ----------------
__global__ __launch_bounds__(256) void k_final(const float* __restrict__ rsum,
    const float* __restrict__ rxsq, const float* __restrict__ musq,
    const float* __restrict__ t1, float* __restrict__ out)
{
    int k = blockIdx.x, tid = threadIdx.x;
    float rs = rsum[k];
    float ts = (rxsq[k] - rs*musq[k]) / rs;
    float sig = (ts - t1[k]) / (float)DIM;
    float ld = logf(sig);
    for (int dd = tid; dd < DIM; dd += 256)
        out[OU_LD + (size_t)k*DIM + dd] = ld;
    if (tid == 0) {
        float s = 0.f;
        for (int j = 0; j < KC; j++) s += rsum[j];
        out[OU_PI + k] = logf(rs / s);
    }
}

extern "C" void kernel_launch(void* const* d_in, const int* in_sizes, int n_in,
                              void* d_out, int out_size, void* d_ws, size_t ws_size,
                              hipStream_t stream) {
    const float* x    = (const float*)d_in[0];
    const float* MU   = (const float*)d_in[1];
    const float* A    = (const float*)d_in[2];
    const float* logD = (const float*)d_in[3];
    const float* PIl  = (const float*)d_in[4];
    float* out = (float*)d_out;
    float* ws  = (float*)d_ws;

    hipMemsetAsync(ws + ZERO_START, 0, (size_t)ZERO_COUNT*sizeof(float), stream);

    k_conv<<<N_ROWS/64, 256, 0, stream>>>(x, ws);
    k_prep<<<KC, 256, 0, stream>>>(MU, A, logD, PIl, ws);
    k_inv16<<<KC, 256, 0, stream>>>(ws + O_LMAT, ws + O_IL, ws + O_LDET);
    k_inv16<<<KC, 256, 0, stream>>>(ws + O_M0, ws + O_INVM, nullptr);
    k_prep2<<<1, 32, 0, stream>>>(ws);

    k_g1f<<<dim3(N_ROWS/128, 4), 256, 0, stream>>>(
        (const ushort*)(ws + O_XH), (const ushort*)(ws + O_XL),
        (const ushort*)(ws + O_WETH), (const ushort*)(ws + O_WETL),
        ws + O_Y);
    k_aux<<<N_ROWS/128, 256, 0, stream>>>(
        (const ushort*)(ws + O_XH), (const ushort*)(ws + O_XL),
        (const ushort*)(ws + O_X2H), (const ushort*)(ws + O_CRH),
        (const ushort*)(ws + O_CRL), (const ushort*)(ws + O_IDC),
        ws + O_AUX);

    k_epiE<<<N_ROWS/32, 256, 0, stream>>>(ws + O_Y, ws + O_AUX, ws + O_IL,
                                          ws + O_CB, ws + O_CK, ws + O_XSQ,
                                          ws + O_R, ws + O_RSUM, ws + O_RXSQ);

    k_mu<<<dim3(8, 32), 256, 0, stream>>>(x, ws + O_R, ws + O_MUACC);
    k_mufin<<<KC, 256, 0, stream>>>(ws + O_MUACC, ws + O_RSUM, A,
                                    out + OU_MU, ws + O_CA, ws + O_MUSQ);

    k_gemm_rq<<<dim3(N_ROWS/128, 4), 256, 0, stream>>>(
        (const ushort*)(ws + O_XH), (const ushort*)(ws + O_AQT),
        ws + O_R, ws + O_CA, (ushort*)(ws + O_RQT), ws + O_SUMRQ);

    k_gemm_sz<<<dim3(8, 4, 16), 256, 0, stream>>>(
        (const ushort*)(ws + O_XBT), (const ushort*)(ws + O_RQT), ws + O_Y);
    k_sired<<<DIM*512/256, 256, 0, stream>>>(ws + O_Y, ws + O_SIAI);

    k_ats1<<<dim3(KC, 8), 256, 0, stream>>>(A, ws + O_SIAI, ws + O_ATS);
    k_ats2<<<KC, 256, 0, stream>>>(ws + O_ATS, logD, ws + O_CA, ws + O_SUMRQ,
                                   ws + O_RSUM, ws + O_INVM, ws + O_GM);
    k_inv16<<<KC, 256, 0, stream>>>(ws + O_GM, ws + O_IG, nullptr);
    k_anew<<<dim3(KC, 4), 256, 0, stream>>>(ws + O_SIAI, out + OU_MU, ws + O_SUMRQ,
                                            ws + O_RSUM, ws + O_IG, ws + O_INVM,
                                            out + OU_A, ws + O_T1);
    k_final<<<KC, 256, 0, stream>>>(ws + O_RSUM, ws + O_RXSQ, ws + O_MUSQ,
                                    ws + O_T1, out);
}